// Round 1
// 840.280 us; speedup vs baseline: 1.0429x; 1.0429x over previous
//
#include <hip/hip_runtime.h>

#define HID 128

typedef __attribute__((ext_vector_type(8))) short short8;
typedef __attribute__((ext_vector_type(4))) float f32x4;
typedef __attribute__((ext_vector_type(2))) float f32x2;

__device__ __forceinline__ float bf2f(unsigned short u) {
  union { unsigned int u; float f; } c; c.u = ((unsigned int)u) << 16; return c.f;
}
__device__ __forceinline__ unsigned short f2bf(float f) {
  union { float f; unsigned int u; } c; c.f = f;
  unsigned int u = c.u;
  return (unsigned short)((u + 0x7FFFu + ((u >> 16) & 1u)) >> 16);  // RNE
}
__device__ __forceinline__ float loads(const void* p, size_t i, bool f32) {
  return f32 ? ((const float*)p)[i] : bf2f(((const unsigned short*)p)[i]);
}
__device__ __forceinline__ short8 load_a8(const void* base, size_t row, int k, bool f32) {
  if (!f32) return *(const short8*)((const unsigned short*)base + row * HID + k);
  const float* fp = (const float*)base + row * HID + k;
  f32x4 f0 = *(const f32x4*)fp;
  f32x4 f1 = *(const f32x4*)(fp + 4);
  short8 t;
  t[0] = (short)f2bf(f0[0]); t[1] = (short)f2bf(f0[1]);
  t[2] = (short)f2bf(f0[2]); t[3] = (short)f2bf(f0[3]);
  t[4] = (short)f2bf(f1[0]); t[5] = (short)f2bf(f1[1]);
  t[6] = (short)f2bf(f1[2]); t[7] = (short)f2bf(f1[3]);
  return t;
}

// ---------------------------------------------------------------------------
// Runtime dtype detection. flags[0]=1 -> fp32 floats; flags[1]=1 -> int64 idx.
// ---------------------------------------------------------------------------
__global__ void detect_kernel(const void* __restrict__ x,
                              const int* __restrict__ eidx,
                              int* __restrict__ flags) {
  __shared__ int bad, oddnz;
  if (threadIdx.x == 0) { bad = 0; oddnz = 0; }
  __syncthreads();
  const unsigned short* xu = (const unsigned short*)x;
  int mybad = 0;
  for (int i = threadIdx.x; i < 4096; i += 256) {
    int ef = (xu[i] >> 7) & 0xFF;
    if (!(ef == 0 || (ef >= 90 && ef <= 140))) mybad++;
  }
  if (mybad) atomicAdd(&bad, mybad);
  if (threadIdx.x < 128) {
    if (eidx[2 * threadIdx.x + 1] != 0) atomicAdd(&oddnz, 1);
  }
  __syncthreads();
  if (threadIdx.x == 0) {
    flags[0] = (bad > 409) ? 1 : 0;
    flags[1] = (oddnz == 0) ? 1 : 0;
  }
}

__device__ __forceinline__ int get_dst(const int* eidx, bool i64, int E, int e) {
  return i64 ? eidx[2 * (E + e)] : eidx[E + e];
}
__device__ __forceinline__ int get_src(const int* eidx, bool i64, int E, int e) {
  return i64 ? eidx[2 * e] : eidx[e];
}

__global__ void zero_out_kernel(unsigned int* __restrict__ out,
                                const int* __restrict__ flags, long long nelem) {
  bool f32 = flags[0] != 0;
  size_t words = (size_t)nelem * (f32 ? 2 : 1) / 2;
  for (size_t w = blockIdx.x * 256ull + threadIdx.x; w < words; w += (size_t)gridDim.x * 256ull)
    out[w] = 0u;
}

// ---------------------------------------------------------------------------
// Repack weights into MFMA B-fragment order (bf16).
// ---------------------------------------------------------------------------
__global__ void repack_all(const void* __restrict__ W1, const void* __restrict__ W2,
                           const void* __restrict__ U1, const void* __restrict__ U2,
                           unsigned short* __restrict__ P1, unsigned short* __restrict__ P2,
                           unsigned short* __restrict__ PU1, unsigned short* __restrict__ PU2,
                           const int* __restrict__ flags) {
  const bool f32 = flags[0] != 0;
  int idx = blockIdx.x * 256 + threadIdx.x;
  const int s1 = 384 * 128, s2 = s1 + 128 * 128, s3 = s2 + 256 * 128, s4 = s3 + 128 * 128;
  if (idx >= s4) return;
  const void* W; unsigned short* P; int off;
  if (idx < s1)      { W = W1; P = P1;  off = idx; }
  else if (idx < s2) { W = W2; P = P2;  off = idx - s1; }
  else if (idx < s3) { W = U1; P = PU1; off = idx - s2; }
  else               { W = U2; P = PU2; off = idx - s3; }
  int j = off & 7, lane = (off >> 3) & 63, ct = (off >> 9) & 7, ks = off >> 12;
  int k = ks * 32 + ((lane >> 4) << 3) + j;
  int n = ct * 16 + (lane & 15);
  P[off] = f2bf(loads(W, (size_t)k * 128 + n, f32));
}

// ---------------------------------------------------------------------------
// Sort machinery: histogram, multi-block 3-phase scan, rank scatter.
// ---------------------------------------------------------------------------
__global__ void hist_kernel(const int* __restrict__ eidx, int* __restrict__ counts,
                            const int* __restrict__ flags, int E, int N) {
  const bool i64 = flags[1] != 0;
  int e = blockIdx.x * 256 + threadIdx.x;
  if (e < E) {
    int d = get_dst(eidx, i64, E, e);
    d = min(max(d, 0), N - 1);
    atomicAdd(&counts[d], 1);
  }
}

// Phase A: per-1024-block exclusive scan -> curb; block totals -> bsum.
__global__ __launch_bounds__(1024) void scanA_kernel(const int* __restrict__ cnt,
                                                     int* __restrict__ curb,
                                                     int* __restrict__ bsum, int N) {
  __shared__ int wsum[16], wsum2[16];
  const int tid = threadIdx.x, lane = tid & 63, wid = tid >> 6;
  int i = blockIdx.x * 1024 + tid;
  int v = (i < N) ? cnt[i] : 0;
  int s = v;
#pragma unroll
  for (int off = 1; off < 64; off <<= 1) {
    int t = __shfl_up(s, off, 64);
    if (lane >= off) s += t;
  }
  if (lane == 63) wsum[wid] = s;
  __syncthreads();
  if (wid == 0 && lane < 16) {
    int w = wsum[lane];
#pragma unroll
    for (int off = 1; off < 16; off <<= 1) {
      int t = __shfl_up(w, off, 16);
      if (lane >= off) w += t;
    }
    wsum2[lane] = w;
    if (lane == 15) bsum[blockIdx.x] = w;
  }
  __syncthreads();
  int pre = (wid > 0) ? wsum2[wid - 1] : 0;
  if (i < N) curb[i] = pre + s - v;
}

// Phase B: serial exclusive scan of block sums (nb small).
__global__ void scanB_kernel(int* __restrict__ bsum, int nb) {
  if (threadIdx.x == 0 && blockIdx.x == 0) {
    int run = 0;
    for (int b = 0; b < nb; b++) { int t = bsum[b]; bsum[b] = run; run += t; }
  }
}

// Phase C: add block offsets.
__global__ __launch_bounds__(1024) void scanC_kernel(int* __restrict__ curb,
                                                     const int* __restrict__ bsum, int N) {
  int i = blockIdx.x * 1024 + threadIdx.x;
  if (i < N) curb[i] += bsum[blockIdx.x];
}

// rank[e] = sorted position. (sdst no longer materialized: the CSR reduce
// derives segment bounds from curb/cntb instead.)
__global__ void scatter_rank_kernel(const int* __restrict__ eidx, int* __restrict__ cur,
                                    int* __restrict__ rank,
                                    const int* __restrict__ flags, int E, int N) {
  const bool i64 = flags[1] != 0;
  int e = blockIdx.x * 256 + threadIdx.x;
  if (e < E) {
    int d = get_dst(eidx, i64, E, e);
    d = min(max(d, 0), N - 1);
    int pos = atomicAdd(&cur[d], 1);
    rank[e] = pos;
  }
}

// ---------------------------------------------------------------------------
// x1_kernel: X1[n] = [ x[n]@W1a + b1 | x[n]@W1b ]  (bf16, N x 256)
// ---------------------------------------------------------------------------
__global__ __launch_bounds__(256) void x1_kernel(
    const void* __restrict__ x, const unsigned short* __restrict__ P1,
    const void* __restrict__ b1, unsigned short* __restrict__ X1,
    const int* __restrict__ flags, int N) {
  __shared__ unsigned short hs[64][264];
  const bool f32 = flags[0] != 0;
  const int tid = threadIdx.x, lane = tid & 63, wid = tid >> 6;
  const int l15 = lane & 15, quad = lane >> 4;
  const int base = blockIdx.x * 64;
  int mn = min(base + wid * 16 + l15, N - 1);

  f32x4 zero = {0.f, 0.f, 0.f, 0.f};
  f32x4 acca[8], accb[8];
#pragma unroll
  for (int ct = 0; ct < 8; ct++) { acca[ct] = zero; accb[ct] = zero; }
#pragma unroll
  for (int ks = 0; ks < 4; ks++) {
    short8 a = load_a8(x, (size_t)mn, ks * 32 + quad * 8, f32);
    const unsigned short* wpa = P1 + ((size_t)(ks * 8) * 64 + lane) * 8;
    const unsigned short* wpb = P1 + ((size_t)((ks + 4) * 8) * 64 + lane) * 8;
#pragma unroll
    for (int ct = 0; ct < 8; ct++) {
      short8 ba = *(const short8*)(wpa + ct * 512);
      short8 bb = *(const short8*)(wpb + ct * 512);
      acca[ct] = __builtin_amdgcn_mfma_f32_16x16x32_bf16(a, ba, acca[ct], 0, 0, 0);
      accb[ct] = __builtin_amdgcn_mfma_f32_16x16x32_bf16(a, bb, accb[ct], 0, 0, 0);
    }
  }
#pragma unroll
  for (int ct = 0; ct < 8; ct++) {
    const int col = ct * 16 + l15;
    const float bv = loads(b1, col, f32);
#pragma unroll
    for (int r = 0; r < 4; r++) {
      hs[wid * 16 + quad * 4 + r][col]       = f2bf(acca[ct][r] + bv);
      hs[wid * 16 + quad * 4 + r][128 + col] = f2bf(accb[ct][r]);
    }
  }
  __syncthreads();
  const int row = tid >> 2, part = tid & 3;
  if (base + row < N) {
    unsigned short* op = X1 + (size_t)(base + row) * 256 + part * 64;
#pragma unroll
    for (int j = 0; j < 8; j++)
      *(short8*)(op + j * 8) = *(const short8*)&hs[row][part * 64 + j * 8];
  }
}

// ---------------------------------------------------------------------------
// edgeB: per 64 unsorted edges: eattr@W1c -> +X1a[src]+X1b[dst] relu -> @W2
// -> bf16 msg scattered to sorted position msgbuf[rank[e]].
// X1 gathers are issued into REGISTERS at kernel start so their ~500-900 cyc
// L2/L3 latency hides under GEMM1 (issue-early / consume-late).
// ---------------------------------------------------------------------------
__global__ __launch_bounds__(256) void edgeB_kernel(
    const void* __restrict__ eattr, const int* __restrict__ eidx,
    const int* __restrict__ rank, const unsigned short* __restrict__ X1,
    const unsigned short* __restrict__ P1, const unsigned short* __restrict__ P2,
    unsigned short* __restrict__ msgbuf, const int* __restrict__ flags, int E, int N) {
  __shared__ unsigned short hsb[64][136];
  __shared__ int rank_s[64];
  const bool f32 = flags[0] != 0;
  const bool i64 = flags[1] != 0;
  const int tid = threadIdx.x, lane = tid & 63, wid = tid >> 6;
  const int l15 = lane & 15, quad = lane >> 4;
  const int base = blockIdx.x * 64;

  if (tid < 64) rank_s[tid] = rank[min(base + tid, E - 1)];

  // --- early X1 gather prefetch (add-phase mapping: r = it*16 + gr, col cg) ---
  const int gr = tid >> 4;          // 0..15
  const int cg = (tid & 15) * 8;    // column group (8 bf16 = 16 B)
  short8 ga[4], gb[4];
#pragma unroll
  for (int it = 0; it < 4; it++) {
    const int e = min(base + it * 16 + gr, E - 1);
    int s = get_src(eidx, i64, E, e);
    int d = get_dst(eidx, i64, E, e);
    s = min(max(s, 0), N - 1);
    d = min(max(d, 0), N - 1);
    ga[it] = *(const short8*)(X1 + (size_t)s * 256 + cg);
    gb[it] = *(const short8*)(X1 + (size_t)d * 256 + 128 + cg);
  }

  int me = min(base + wid * 16 + l15, E - 1);
  f32x4 zero = {0.f, 0.f, 0.f, 0.f};
  f32x4 acc[8];
#pragma unroll
  for (int ct = 0; ct < 8; ct++) acc[ct] = zero;
  // eattr @ W1c  (W1 rows 256..383 = P1 ks 8..11); eattr rows consecutive.
#pragma unroll
  for (int ks = 0; ks < 4; ks++) {
    short8 a = load_a8(eattr, (size_t)me, ks * 32 + quad * 8, f32);
    const unsigned short* wp = P1 + ((size_t)((ks + 8) * 8) * 64 + lane) * 8;
#pragma unroll
    for (int ct = 0; ct < 8; ct++) {
      short8 b = *(const short8*)(wp + ct * 512);
      acc[ct] = __builtin_amdgcn_mfma_f32_16x16x32_bf16(a, b, acc[ct], 0, 0, 0);
    }
  }
#pragma unroll
  for (int ct = 0; ct < 8; ct++) {
    const int col = ct * 16 + l15;
#pragma unroll
    for (int r = 0; r < 4; r++)
      hsb[wid * 16 + quad * 4 + r][col] = f2bf(acc[ct][r]);
  }
  __syncthreads();

  // Add prefetched X1a[src] + X1b[dst], ReLU (registers, no re-gather).
#pragma unroll
  for (int it = 0; it < 4; it++) {
    const int r = it * 16 + gr;
    short8 h8 = *(const short8*)&hsb[r][cg];
    short8 a8 = ga[it];
    short8 b8 = gb[it];
    short8 o;
#pragma unroll
    for (int j = 0; j < 8; j++) {
      float v = bf2f((unsigned short)h8[j]) + bf2f((unsigned short)a8[j])
              + bf2f((unsigned short)b8[j]);
      o[j] = (short)f2bf(fmaxf(v, 0.f));
    }
    *(short8*)&hsb[r][cg] = o;
  }
  __syncthreads();

  // GEMM2: h @ W2 (wave-private rows).
  f32x4 acc2[8];
#pragma unroll
  for (int ct = 0; ct < 8; ct++) acc2[ct] = zero;
#pragma unroll
  for (int ks = 0; ks < 4; ks++) {
    short8 a = *(const short8*)&hsb[wid * 16 + l15][ks * 32 + quad * 8];
    const unsigned short* wp = P2 + ((size_t)(ks * 8) * 64 + lane) * 8;
#pragma unroll
    for (int ct = 0; ct < 8; ct++) {
      short8 b = *(const short8*)(wp + ct * 512);
      acc2[ct] = __builtin_amdgcn_mfma_f32_16x16x32_bf16(a, b, acc2[ct], 0, 0, 0);
    }
  }
#pragma unroll
  for (int ct = 0; ct < 8; ct++) {
    const int col = ct * 16 + l15;
#pragma unroll
    for (int r = 0; r < 4; r++)
      hsb[wid * 16 + quad * 4 + r][col] = f2bf(acc2[ct][r]);  // b2 folded in reduce
  }
  __syncthreads();

  const int row = tid >> 2, part = tid & 3;
  if (base + row < E) {
    unsigned short* mp = msgbuf + (size_t)rank_s[row] * HID + part * 32;
#pragma unroll
    for (int j = 0; j < 4; j++)
      *(short8*)(mp + j * 8) = *(const short8*)&hsb[row][part * 32 + j * 8];
  }
}

// ---------------------------------------------------------------------------
// reduce_csr: per-node wave reduce over the sorted msgbuf segment
// [curb[d]-cntb[d], curb[d]).  Coalesced 256 B row reads, NON-ATOMIC writes,
// b2 folded as cnt*b2.  Replaces the 7.7M-atomic segmented reduce.
// ---------------------------------------------------------------------------
__global__ __launch_bounds__(256) void reduce_csr_kernel(
    const unsigned short* __restrict__ msgbuf, const int* __restrict__ curb,
    const int* __restrict__ cntb, const void* __restrict__ b2,
    float* __restrict__ aggf, const int* __restrict__ flags, int N) {
  const bool f32 = flags[0] != 0;
  const int lane = threadIdx.x & 63, wid = threadIdx.x >> 6;
  const int d = blockIdx.x * 4 + wid;
  if (d >= N) return;
  const int cnt = cntb[d];
  const int end = curb[d];
  const int beg = end - cnt;
  const int c0 = lane * 2;
  float sa0 = 0.f, sb0 = 0.f, sa1 = 0.f, sb1 = 0.f;
  int p = beg;
  for (; p + 2 <= end; p += 2) {
    unsigned int u0 = *(const unsigned int*)(msgbuf + (size_t)p * HID + c0);
    unsigned int u1 = *(const unsigned int*)(msgbuf + (size_t)(p + 1) * HID + c0);
    sa0 += bf2f((unsigned short)(u0 & 0xFFFF));
    sb0 += bf2f((unsigned short)(u0 >> 16));
    sa1 += bf2f((unsigned short)(u1 & 0xFFFF));
    sb1 += bf2f((unsigned short)(u1 >> 16));
  }
  if (p < end) {
    unsigned int u = *(const unsigned int*)(msgbuf + (size_t)p * HID + c0);
    sa0 += bf2f((unsigned short)(u & 0xFFFF));
    sb0 += bf2f((unsigned short)(u >> 16));
  }
  f32x2 o;
  o.x = sa0 + sa1 + cnt * loads(b2, c0, f32);
  o.y = sb0 + sb1 + cnt * loads(b2, c0 + 1, f32);
  *(f32x2*)(aggf + (size_t)d * HID + c0) = o;
}

// ---------------------------------------------------------------------------
// Mode-2 fallback kernels (round-3 structure, kept intact).
// ---------------------------------------------------------------------------
__global__ __launch_bounds__(1024) void scan_kernel(const int* __restrict__ counts,
                                                    int* __restrict__ offs, int N) {
  __shared__ int wsum[16];
  __shared__ int wpre[16];
  __shared__ int carry_s;
  const int tid = threadIdx.x, lane = tid & 63, wid = tid >> 6;
  if (tid == 0) carry_s = 0;
  __syncthreads();
  for (int base = 0; base < N; base += 1024) {
    int i = base + tid;
    int v = (i < N) ? counts[i] : 0;
    int s = v;
#pragma unroll
    for (int off = 1; off < 64; off <<= 1) {
      int t = __shfl_up(s, off, 64);
      if (lane >= off) s += t;
    }
    if (lane == 63) wsum[wid] = s;
    __syncthreads();
    if (tid == 0) {
      int run = carry_s;
#pragma unroll
      for (int w = 0; w < 16; w++) { int t = wsum[w]; wpre[w] = run; run += t; }
      carry_s = run;
    }
    __syncthreads();
    if (i < N) offs[i] = wpre[wid] + s - v;
    __syncthreads();
  }
  if (tid == 0) offs[N] = carry_s;
}

__global__ void scatter_kernel(const int* __restrict__ eidx, int* __restrict__ cur,
                               int* __restrict__ ssrc, int* __restrict__ sdst,
                               int* __restrict__ perm,
                               const int* __restrict__ flags, int E, int N) {
  const bool i64 = flags[1] != 0;
  int e = blockIdx.x * 256 + threadIdx.x;
  if (e < E) {
    int d = get_dst(eidx, i64, E, e);
    int s = get_src(eidx, i64, E, e);
    d = min(max(d, 0), N - 1);
    s = min(max(s, 0), N - 1);
    int pos = atomicAdd(&cur[d], 1);
    ssrc[pos] = s;
    sdst[pos] = d;
    perm[pos] = e;
  }
}

__global__ __launch_bounds__(256) void edge_kernel_sorted(
    const void* __restrict__ x, const void* __restrict__ eattr,
    const int* __restrict__ ssrc, const int* __restrict__ sdst,
    const int* __restrict__ perm,
    const unsigned short* __restrict__ P1, const void* __restrict__ b1,
    const unsigned short* __restrict__ P2, const void* __restrict__ b2,
    float* __restrict__ aggf, const int* __restrict__ flags, int E, int N) {
  __shared__ __align__(16) char smem[64 * 132 * 4];
  __shared__ int sdst_s[64];
  unsigned short (*hs)[136] = (unsigned short (*)[136])smem;
  float (*ms)[132] = (float (*)[132])smem;
  const bool f32 = flags[0] != 0;
  const int tid = threadIdx.x, lane = tid & 63, wid = tid >> 6;
  const int l15 = lane & 15, quad = lane >> 4;
  const int base = blockIdx.x * 64;

  if (tid < 64) sdst_s[tid] = sdst[min(base + tid, E - 1)];

  int me = base + wid * 16 + l15;
  if (me >= E) me = E - 1;
  const int src = ssrc[me];
  const int dsm = sdst[me];
  const int pe  = perm[me];

  f32x4 zero = {0.f, 0.f, 0.f, 0.f};
  f32x4 acc[8];
#pragma unroll
  for (int ct = 0; ct < 8; ct++) acc[ct] = zero;
#pragma unroll
  for (int ks = 0; ks < 12; ks++) {
    const int k0 = ks * 32;
    short8 a;
    if (k0 < 128)      a = load_a8(x,     (size_t)src, k0 + quad * 8, f32);
    else if (k0 < 256) a = load_a8(x,     (size_t)dsm, (k0 - 128) + quad * 8, f32);
    else               a = load_a8(eattr, (size_t)pe,  (k0 - 256) + quad * 8, f32);
    const unsigned short* wp = P1 + ((size_t)(ks * 8) * 64 + lane) * 8;
#pragma unroll
    for (int ct = 0; ct < 8; ct++) {
      short8 b = *(const short8*)(wp + ct * 512);
      acc[ct] = __builtin_amdgcn_mfma_f32_16x16x32_bf16(a, b, acc[ct], 0, 0, 0);
    }
  }
#pragma unroll
  for (int ct = 0; ct < 8; ct++) {
    const int col = ct * 16 + l15;
    const float bv = loads(b1, col, f32);
#pragma unroll
    for (int r = 0; r < 4; r++)
      hs[wid * 16 + quad * 4 + r][col] = f2bf(fmaxf(acc[ct][r] + bv, 0.f));
  }
  f32x4 acc2[8];
#pragma unroll
  for (int ct = 0; ct < 8; ct++) acc2[ct] = zero;
#pragma unroll
  for (int ks = 0; ks < 4; ks++) {
    short8 a = *(const short8*)&hs[wid * 16 + l15][ks * 32 + quad * 8];
    const unsigned short* wp = P2 + ((size_t)(ks * 8) * 64 + lane) * 8;
#pragma unroll
    for (int ct = 0; ct < 8; ct++) {
      short8 b = *(const short8*)(wp + ct * 512);
      acc2[ct] = __builtin_amdgcn_mfma_f32_16x16x32_bf16(a, b, acc2[ct], 0, 0, 0);
    }
  }
  float b2v[8];
#pragma unroll
  for (int ct = 0; ct < 8; ct++) b2v[ct] = loads(b2, ct * 16 + l15, f32);
  __syncthreads();
#pragma unroll
  for (int ct = 0; ct < 8; ct++) {
    const int col = ct * 16 + l15;
#pragma unroll
    for (int r = 0; r < 4; r++) {
      const int e = base + wid * 16 + quad * 4 + r;
      ms[wid * 16 + quad * 4 + r][col] = (e < E) ? (acc2[ct][r] + b2v[ct]) : 0.0f;
    }
  }
  __syncthreads();
  const int col  = tid & 127;
  const int half = tid >> 7;
  const int r0 = half * 32;
  float sum = 0.0f;
  int cur = sdst_s[r0];
#pragma unroll 4
  for (int r = r0; r < r0 + 32; r++) {
    int d = sdst_s[r];
    if (d != cur) {
      atomicAdd(&aggf[(size_t)cur * HID + col], sum);
      sum = 0.0f; cur = d;
    }
    sum += ms[r][col];
  }
  atomicAdd(&aggf[(size_t)cur * HID + col], sum);
}

__global__ __launch_bounds__(256) void edge_kernel_plain(
    const void* __restrict__ x, const int* __restrict__ eidx,
    const void* __restrict__ eattr,
    const unsigned short* __restrict__ P1, const void* __restrict__ b1,
    const unsigned short* __restrict__ P2, const void* __restrict__ b2,
    float* __restrict__ aggf, void* __restrict__ out,
    const int* __restrict__ flags, int E, int N, int small_mode) {
  __shared__ unsigned short hs[64][136];
  const bool f32 = flags[0] != 0;
  const bool i64 = flags[1] != 0;
  const int tid = threadIdx.x, lane = tid & 63, wid = tid >> 6;
  const int l15 = lane & 15, quad = lane >> 4;
  const int base = blockIdx.x * 64;

  int me = base + wid * 16 + l15;
  if (me >= E) me = E - 1;
  int src = get_src(eidx, i64, E, me);
  int dsm = get_dst(eidx, i64, E, me);
  src = min(max(src, 0), N - 1);
  dsm = min(max(dsm, 0), N - 1);

  f32x4 zero = {0.f, 0.f, 0.f, 0.f};
  f32x4 acc[8];
#pragma unroll
  for (int ct = 0; ct < 8; ct++) acc[ct] = zero;
#pragma unroll
  for (int ks = 0; ks < 12; ks++) {
    const int k0 = ks * 32;
    short8 a;
    if (k0 < 128)      a = load_a8(x,     (size_t)src, k0 + quad * 8, f32);
    else if (k0 < 256) a = load_a8(x,     (size_t)dsm, (k0 - 128) + quad * 8, f32);
    else               a = load_a8(eattr, (size_t)me,  (k0 - 256) + quad * 8, f32);
    const unsigned short* wp = P1 + ((size_t)(ks * 8) * 64 + lane) * 8;
#pragma unroll
    for (int ct = 0; ct < 8; ct++) {
      short8 b = *(const short8*)(wp + ct * 512);
      acc[ct] = __builtin_amdgcn_mfma_f32_16x16x32_bf16(a, b, acc[ct], 0, 0, 0);
    }
  }
#pragma unroll
  for (int ct = 0; ct < 8; ct++) {
    const int col = ct * 16 + l15;
    const float bv = loads(b1, col, f32);
#pragma unroll
    for (int r = 0; r < 4; r++)
      hs[wid * 16 + quad * 4 + r][col] = f2bf(fmaxf(acc[ct][r] + bv, 0.f));
  }
  __syncthreads();
  f32x4 acc2[8];
#pragma unroll
  for (int ct = 0; ct < 8; ct++) acc2[ct] = zero;
#pragma unroll
  for (int ks = 0; ks < 4; ks++) {
    short8 a = *(const short8*)&hs[wid * 16 + l15][ks * 32 + quad * 8];
    const unsigned short* wp = P2 + ((size_t)(ks * 8) * 64 + lane) * 8;
#pragma unroll
    for (int ct = 0; ct < 8; ct++) {
      short8 b = *(const short8*)(wp + ct * 512);
      acc2[ct] = __builtin_amdgcn_mfma_f32_16x16x32_bf16(a, b, acc2[ct], 0, 0, 0);
    }
  }
  float b2v[8];
#pragma unroll
  for (int ct = 0; ct < 8; ct++) b2v[ct] = loads(b2, ct * 16 + l15, f32);

  if (!small_mode || f32) {
    float* tgt = (!small_mode) ? aggf : (float*)out;
#pragma unroll
    for (int r = 0; r < 4; r++) {
      const int e = base + wid * 16 + quad * 4 + r;
      if (e < E) {
        int d = get_dst(eidx, i64, E, e);
        d = min(max(d, 0), N - 1);
        float* op = tgt + (size_t)d * HID + l15;
#pragma unroll
        for (int ct = 0; ct < 8; ct++) atomicAdd(op + ct * 16, acc2[ct][r] + b2v[ct]);
      }
    }
  } else {
#pragma unroll
    for (int ct = 0; ct < 8; ct++) {
      const int col = ct * 16 + l15;
#pragma unroll
      for (int r = 0; r < 4; r++)
        hs[wid * 16 + quad * 4 + r][col] = f2bf(acc2[ct][r] + b2v[ct]);
    }
    __syncthreads();
    const int row = tid >> 2;
    const int cg  = (tid & 3) * 32;
    const int e = base + row;
    if (e < E) {
      int d = get_dst(eidx, i64, E, e);
      d = min(max(d, 0), N - 1);
      unsigned int* orow = (unsigned int*)out + ((size_t)d * HID >> 1);
#pragma unroll
      for (int p = 0; p < 16; p++) {
        const int col = cg + p * 2;
        const float lo = bf2f(hs[row][col]);
        const float hi = bf2f(hs[row][col + 1]);
        unsigned int* wp = orow + (col >> 1);
        unsigned int old = *wp, assumed;
        do {
          assumed = old;
          unsigned int nv = (unsigned int)f2bf(bf2f((unsigned short)(assumed & 0xFFFF)) + lo)
                          | ((unsigned int)f2bf(bf2f((unsigned short)(assumed >> 16)) + hi) << 16);
          old = atomicCAS(wp, assumed, nv);
        } while (old != assumed);
      }
    }
  }
}

// ---------------------------------------------------------------------------
// Node kernel: u = relu([x|agg]@U1+ub1); upd = u@U2+ub2; out = LN(x+upd)*g+b
// ---------------------------------------------------------------------------
__global__ __launch_bounds__(256) void node_kernel(
    const void* __restrict__ x, const float* __restrict__ aggf,
    const unsigned short* __restrict__ PU1, const void* __restrict__ ub1,
    const unsigned short* __restrict__ PU2, const void* __restrict__ ub2,
    const void* __restrict__ gamma, const void* __restrict__ beta,
    void* __restrict__ out, const int* __restrict__ flags, int N, int small_mode) {
  __shared__ unsigned short hs[64][136];
  const bool f32 = flags[0] != 0;
  const int tid = threadIdx.x, lane = tid & 63, wid = tid >> 6;
  const int l15 = lane & 15, quad = lane >> 4;
  const int base = blockIdx.x * 64;

  int mn = base + wid * 16 + l15;
  if (mn >= N) mn = N - 1;

  const void* aggp = (!small_mode) ? (const void*)aggf : (const void*)out;
  const bool aggF32 = (!small_mode) ? true : f32;

  f32x4 zero = {0.f, 0.f, 0.f, 0.f};
  f32x4 acc[8];
#pragma unroll
  for (int ct = 0; ct < 8; ct++) acc[ct] = zero;
#pragma unroll
  for (int ks = 0; ks < 8; ks++) {
    const int k0 = ks * 32;
    short8 a;
    if (k0 < 128) a = load_a8(x,    (size_t)mn, k0 + quad * 8, f32);
    else          a = load_a8(aggp, (size_t)mn, (k0 - 128) + quad * 8, aggF32);
    const unsigned short* wp = PU1 + ((size_t)(ks * 8) * 64 + lane) * 8;
#pragma unroll
    for (int ct = 0; ct < 8; ct++) {
      short8 b = *(const short8*)(wp + ct * 512);
      acc[ct] = __builtin_amdgcn_mfma_f32_16x16x32_bf16(a, b, acc[ct], 0, 0, 0);
    }
  }
#pragma unroll
  for (int ct = 0; ct < 8; ct++) {
    const int col = ct * 16 + l15;
    const float bv = loads(ub1, col, f32);
#pragma unroll
    for (int r = 0; r < 4; r++)
      hs[wid * 16 + quad * 4 + r][col] = f2bf(fmaxf(acc[ct][r] + bv, 0.f));
  }
  __syncthreads();
  f32x4 acc2[8];
#pragma unroll
  for (int ct = 0; ct < 8; ct++) acc2[ct] = zero;
#pragma unroll
  for (int ks = 0; ks < 4; ks++) {
    short8 a = *(const short8*)&hs[wid * 16 + l15][ks * 32 + quad * 8];
    const unsigned short* wp = PU2 + ((size_t)(ks * 8) * 64 + lane) * 8;
#pragma unroll
    for (int ct = 0; ct < 8; ct++) {
      short8 b = *(const short8*)(wp + ct * 512);
      acc2[ct] = __builtin_amdgcn_mfma_f32_16x16x32_bf16(a, b, acc2[ct], 0, 0, 0);
    }
  }

  float vals[8][4];
  float s1[4] = {0.f, 0.f, 0.f, 0.f};
  float s2[4] = {0.f, 0.f, 0.f, 0.f};
#pragma unroll
  for (int ct = 0; ct < 8; ct++) {
    const int col = ct * 16 + l15;
    const float bv = loads(ub2, col, f32);
#pragma unroll
    for (int r = 0; r < 4; r++) {
      int row = base + wid * 16 + quad * 4 + r;
      int rc = row < N ? row : 0;
      float v = acc2[ct][r] + bv + loads(x, (size_t)rc * HID + col, f32);
      vals[ct][r] = v;
      s1[r] += v;
      s2[r] += v * v;
    }
  }
#pragma unroll
  for (int off = 1; off < 16; off <<= 1) {
#pragma unroll
    for (int r = 0; r < 4; r++) {
      s1[r] += __shfl_xor(s1[r], off, 16);
      s2[r] += __shfl_xor(s2[r], off, 16);
    }
  }
#pragma unroll
  for (int r = 0; r < 4; r++) {
    const int row = base + wid * 16 + quad * 4 + r;
    if (row < N) {
      const float mean = s1[r] * (1.0f / 128.0f);
      const float var  = fmaxf(s2[r] * (1.0f / 128.0f) - mean * mean, 0.0f);
      const float rstd = rsqrtf(var + 1e-5f);
#pragma unroll
      for (int ct = 0; ct < 8; ct++) {
        const int col = ct * 16 + l15;
        float o = (vals[ct][r] - mean) * rstd * loads(gamma, col, f32) + loads(beta, col, f32);
        if (f32) ((float*)out)[(size_t)row * HID + col] = o;
        else     ((unsigned short*)out)[(size_t)row * HID + col] = f2bf(o);
      }
    }
  }
}

// ---------------------------------------------------------------------------
extern "C" void kernel_launch(void* const* d_in, const int* in_sizes, int n_in,
                              void* d_out, int out_size, void* d_ws, size_t ws_size,
                              hipStream_t stream) {
  (void)n_in;
  const void* x     = d_in[0];
  const int*  eidx  = (const int*)d_in[1];
  const void* eattr = d_in[2];
  const void* W1  = d_in[3];
  const void* b1  = d_in[4];
  const void* W2  = d_in[5];
  const void* b2  = d_in[6];
  const void* U1  = d_in[7];
  const void* ub1 = d_in[8];
  const void* U2  = d_in[9];
  const void* ub2 = d_in[10];
  const void* gam = d_in[11];
  const void* bet = d_in[12];

  const int N = in_sizes[0] / HID;
  const int E = in_sizes[2] / HID;

  char* ws = (char*)d_ws;
  auto alignup = [](size_t v) { return (v + 255) & ~(size_t)255; };

  int* flags = (int*)ws;                                       // 256 B
  unsigned short* P1  = (unsigned short*)(ws + 256);
  unsigned short* P2  = (unsigned short*)(ws + 256 + 98304);
  unsigned short* PU1 = (unsigned short*)(ws + 256 + 131072);
  unsigned short* PU2 = (unsigned short*)(ws + 256 + 196608);
  const size_t agg_off = 256 + 229376;
  float* aggf = (float*)(ws + agg_off);
  const size_t agg_bytes = (size_t)N * HID * sizeof(float);
  const size_t need_basic = agg_off + agg_bytes;

  // ---- mode-3 layout ----
  size_t o3 = alignup(need_basic);
  size_t cnt_off  = o3; o3 = alignup(o3 + (size_t)(N + 64) * 4);
  size_t cur_off  = o3; o3 = alignup(o3 + (size_t)(N + 64) * 4);
  size_t bsum_off = o3; o3 = alignup(o3 + 1024);
  size_t rank_off = o3; o3 = alignup(o3 + (size_t)E * 4);
  size_t x1_off   = o3; o3 = alignup(o3 + (size_t)N * 256 * 2);
  size_t msg_off  = o3; o3 = alignup(o3 + (size_t)E * HID * 2);
  const size_t need3 = o3;

  // ---- mode-2 layout (round-3) ----
  size_t o2 = alignup(need_basic);
  size_t offs_off = o2; o2 = alignup(o2 + (size_t)(N + 1) * 4);
  size_t cur2_off = o2; o2 = alignup(o2 + (size_t)(N + 1) * 4);
  size_t ssrc_off = o2; o2 = alignup(o2 + (size_t)E * 4);
  size_t sds2_off = o2; o2 = alignup(o2 + (size_t)E * 4);
  size_t perm_off = o2; o2 = alignup(o2 + (size_t)E * 4);
  const size_t need2 = o2;

  const int mode = (ws_size >= need3) ? 3
                 : (ws_size >= need2) ? 2
                 : (ws_size >= need_basic) ? 1 : 0;

  detect_kernel<<<1, 256, 0, stream>>>(x, eidx, flags);
  repack_all<<<448, 256, 0, stream>>>(W1, W2, U1, U2, P1, P2, PU1, PU2, flags);

  if (mode == 3) {
    int* cntb = (int*)(ws + cnt_off);
    int* curb = (int*)(ws + cur_off);
    int* bsum = (int*)(ws + bsum_off);
    int* rank = (int*)(ws + rank_off);
    unsigned short* X1     = (unsigned short*)(ws + x1_off);
    unsigned short* msgbuf = (unsigned short*)(ws + msg_off);
    const int nb = (N + 1023) / 1024;

    hipMemsetAsync(cntb, 0, (size_t)N * 4, stream);
    hist_kernel<<<(E + 255) / 256, 256, 0, stream>>>(eidx, cntb, flags, E, N);
    scanA_kernel<<<nb, 1024, 0, stream>>>(cntb, curb, bsum, N);
    scanB_kernel<<<1, 64, 0, stream>>>(bsum, nb);
    scanC_kernel<<<nb, 1024, 0, stream>>>(curb, bsum, N);
    scatter_rank_kernel<<<(E + 255) / 256, 256, 0, stream>>>(eidx, curb, rank,
                                                             flags, E, N);
    x1_kernel<<<(N + 63) / 64, 256, 0, stream>>>(x, P1, b1, X1, flags, N);
    edgeB_kernel<<<(E + 63) / 64, 256, 0, stream>>>(eattr, eidx, rank, X1, P1, P2,
                                                    msgbuf, flags, E, N);
    reduce_csr_kernel<<<(N + 3) / 4, 256, 0, stream>>>(msgbuf, curb, cntb, b2, aggf,
                                                       flags, N);
    node_kernel<<<(N + 63) / 64, 256, 0, stream>>>(x, aggf, PU1, ub1, PU2, ub2,
                                                   gam, bet, d_out, flags, N, 0);
  } else if (mode == 2) {
    int* offsb = (int*)(ws + offs_off);
    int* curb  = (int*)(ws + cur2_off);
    int* ssrc  = (int*)(ws + ssrc_off);
    int* sdst  = (int*)(ws + sds2_off);
    int* perm  = (int*)(ws + perm_off);
    hipMemsetAsync(aggf, 0, agg_bytes, stream);
    hipMemsetAsync(curb, 0, (size_t)(N + 1) * 4, stream);
    hist_kernel<<<(E + 255) / 256, 256, 0, stream>>>(eidx, curb, flags, E, N);
    scan_kernel<<<1, 1024, 0, stream>>>(curb, offsb, N);
    hipMemcpyAsync(curb, offsb, (size_t)(N + 1) * 4, hipMemcpyDeviceToDevice, stream);
    scatter_kernel<<<(E + 255) / 256, 256, 0, stream>>>(eidx, curb, ssrc, sdst, perm,
                                                        flags, E, N);
    edge_kernel_sorted<<<(E + 63) / 64, 256, 0, stream>>>(x, eattr, ssrc, sdst, perm,
                                                          P1, b1, P2, b2, aggf, flags, E, N);
    node_kernel<<<(N + 63) / 64, 256, 0, stream>>>(x, aggf, PU1, ub1, PU2, ub2,
                                                   gam, bet, d_out, flags, N, 0);
  } else if (mode == 1) {
    hipMemsetAsync(aggf, 0, agg_bytes, stream);
    edge_kernel_plain<<<(E + 63) / 64, 256, 0, stream>>>(x, eidx, eattr, P1, b1, P2, b2,
                                                         aggf, d_out, flags, E, N, 0);
    node_kernel<<<(N + 63) / 64, 256, 0, stream>>>(x, aggf, PU1, ub1, PU2, ub2,
                                                   gam, bet, d_out, flags, N, 0);
  } else {
    zero_out_kernel<<<1024, 256, 0, stream>>>((unsigned int*)d_out, flags, (long long)out_size);
    edge_kernel_plain<<<(E + 63) / 64, 256, 0, stream>>>(x, eidx, eattr, P1, b1, P2, b2,
                                                         aggf, d_out, flags, E, N, 1);
    node_kernel<<<(N + 63) / 64, 256, 0, stream>>>(x, aggf, PU1, ub1, PU2, ub2,
                                                   gam, bet, d_out, flags, N, 1);
  }
}

// Round 3
// 783.226 us; speedup vs baseline: 1.1189x; 1.0728x over previous
//
#include <hip/hip_runtime.h>

#define HID 128

typedef __attribute__((ext_vector_type(8))) short short8;
typedef __attribute__((ext_vector_type(4))) float f32x4;
typedef __attribute__((ext_vector_type(2))) float f32x2;

__device__ __forceinline__ float bf2f(unsigned short u) {
  union { unsigned int u; float f; } c; c.u = ((unsigned int)u) << 16; return c.f;
}
__device__ __forceinline__ unsigned short f2bf(float f) {
  union { float f; unsigned int u; } c; c.f = f;
  unsigned int u = c.u;
  return (unsigned short)((u + 0x7FFFu + ((u >> 16) & 1u)) >> 16);  // RNE
}
__device__ __forceinline__ float loads(const void* p, size_t i, bool f32) {
  return f32 ? ((const float*)p)[i] : bf2f(((const unsigned short*)p)[i]);
}
__device__ __forceinline__ short8 load_a8(const void* base, size_t row, int k, bool f32) {
  if (!f32) return *(const short8*)((const unsigned short*)base + row * HID + k);
  const float* fp = (const float*)base + row * HID + k;
  f32x4 f0 = *(const f32x4*)fp;
  f32x4 f1 = *(const f32x4*)(fp + 4);
  short8 t;
  t[0] = (short)f2bf(f0[0]); t[1] = (short)f2bf(f0[1]);
  t[2] = (short)f2bf(f0[2]); t[3] = (short)f2bf(f0[3]);
  t[4] = (short)f2bf(f1[0]); t[5] = (short)f2bf(f1[1]);
  t[6] = (short)f2bf(f1[2]); t[7] = (short)f2bf(f1[3]);
  return t;
}

// ---------------------------------------------------------------------------
// Runtime dtype detection. flags[0]=1 -> fp32 floats; flags[1]=1 -> int64 idx.
// ---------------------------------------------------------------------------
__global__ void detect_kernel(const void* __restrict__ x,
                              const int* __restrict__ eidx,
                              int* __restrict__ flags) {
  __shared__ int bad, oddnz;
  if (threadIdx.x == 0) { bad = 0; oddnz = 0; }
  __syncthreads();
  const unsigned short* xu = (const unsigned short*)x;
  int mybad = 0;
  for (int i = threadIdx.x; i < 4096; i += 256) {
    int ef = (xu[i] >> 7) & 0xFF;
    if (!(ef == 0 || (ef >= 90 && ef <= 140))) mybad++;
  }
  if (mybad) atomicAdd(&bad, mybad);
  if (threadIdx.x < 128) {
    if (eidx[2 * threadIdx.x + 1] != 0) atomicAdd(&oddnz, 1);
  }
  __syncthreads();
  if (threadIdx.x == 0) {
    flags[0] = (bad > 409) ? 1 : 0;
    flags[1] = (oddnz == 0) ? 1 : 0;
  }
}

__device__ __forceinline__ int get_dst(const int* eidx, bool i64, int E, int e) {
  return i64 ? eidx[2 * (E + e)] : eidx[E + e];
}
__device__ __forceinline__ int get_src(const int* eidx, bool i64, int E, int e) {
  return i64 ? eidx[2 * e] : eidx[e];
}

__global__ void zero_out_kernel(unsigned int* __restrict__ out,
                                const int* __restrict__ flags, long long nelem) {
  bool f32 = flags[0] != 0;
  size_t words = (size_t)nelem * (f32 ? 2 : 1) / 2;
  for (size_t w = blockIdx.x * 256ull + threadIdx.x; w < words; w += (size_t)gridDim.x * 256ull)
    out[w] = 0u;
}

// ---------------------------------------------------------------------------
// Repack weights into MFMA B-fragment order (bf16).
// ---------------------------------------------------------------------------
__global__ void repack_all(const void* __restrict__ W1, const void* __restrict__ W2,
                           const void* __restrict__ U1, const void* __restrict__ U2,
                           unsigned short* __restrict__ P1, unsigned short* __restrict__ P2,
                           unsigned short* __restrict__ PU1, unsigned short* __restrict__ PU2,
                           const int* __restrict__ flags) {
  const bool f32 = flags[0] != 0;
  int idx = blockIdx.x * 256 + threadIdx.x;
  const int s1 = 384 * 128, s2 = s1 + 128 * 128, s3 = s2 + 256 * 128, s4 = s3 + 128 * 128;
  if (idx >= s4) return;
  const void* W; unsigned short* P; int off;
  if (idx < s1)      { W = W1; P = P1;  off = idx; }
  else if (idx < s2) { W = W2; P = P2;  off = idx - s1; }
  else if (idx < s3) { W = U1; P = PU1; off = idx - s2; }
  else               { W = U2; P = PU2; off = idx - s3; }
  int j = off & 7, lane = (off >> 3) & 63, ct = (off >> 9) & 7, ks = off >> 12;
  int k = ks * 32 + ((lane >> 4) << 3) + j;
  int n = ct * 16 + (lane & 15);
  P[off] = f2bf(loads(W, (size_t)k * 128 + n, f32));
}

// ---------------------------------------------------------------------------
// Sort machinery: histogram, multi-block 3-phase scan, scatter.
// ---------------------------------------------------------------------------
__global__ void hist_kernel(const int* __restrict__ eidx, int* __restrict__ counts,
                            const int* __restrict__ flags, int E, int N) {
  const bool i64 = flags[1] != 0;
  int e = blockIdx.x * 256 + threadIdx.x;
  if (e < E) {
    int d = get_dst(eidx, i64, E, e);
    d = min(max(d, 0), N - 1);
    atomicAdd(&counts[d], 1);
  }
}

// Phase A: per-1024-block exclusive scan -> curb; block totals -> bsum.
__global__ __launch_bounds__(1024) void scanA_kernel(const int* __restrict__ cnt,
                                                     int* __restrict__ curb,
                                                     int* __restrict__ bsum, int N) {
  __shared__ int wsum[16], wsum2[16];
  const int tid = threadIdx.x, lane = tid & 63, wid = tid >> 6;
  int i = blockIdx.x * 1024 + tid;
  int v = (i < N) ? cnt[i] : 0;
  int s = v;
#pragma unroll
  for (int off = 1; off < 64; off <<= 1) {
    int t = __shfl_up(s, off, 64);
    if (lane >= off) s += t;
  }
  if (lane == 63) wsum[wid] = s;
  __syncthreads();
  if (wid == 0 && lane < 16) {
    int w = wsum[lane];
#pragma unroll
    for (int off = 1; off < 16; off <<= 1) {
      int t = __shfl_up(w, off, 16);
      if (lane >= off) w += t;
    }
    wsum2[lane] = w;
    if (lane == 15) bsum[blockIdx.x] = w;
  }
  __syncthreads();
  int pre = (wid > 0) ? wsum2[wid - 1] : 0;
  if (i < N) curb[i] = pre + s - v;
}

// Phase B: serial exclusive scan of block sums (nb small).
__global__ void scanB_kernel(int* __restrict__ bsum, int nb) {
  if (threadIdx.x == 0 && blockIdx.x == 0) {
    int run = 0;
    for (int b = 0; b < nb; b++) { int t = bsum[b]; bsum[b] = run; run += t; }
  }
}

// Phase C: add block offsets.
__global__ __launch_bounds__(1024) void scanC_kernel(int* __restrict__ curb,
                                                     const int* __restrict__ bsum, int N) {
  int i = blockIdx.x * 1024 + threadIdx.x;
  if (i < N) curb[i] += bsum[blockIdx.x];
}

// ---------------------------------------------------------------------------
// x1_kernel: X1[n] = [ x[n]@W1a + b1 | x[n]@W1b ]  (bf16, N x 256)
// ---------------------------------------------------------------------------
__global__ __launch_bounds__(256) void x1_kernel(
    const void* __restrict__ x, const unsigned short* __restrict__ P1,
    const void* __restrict__ b1, unsigned short* __restrict__ X1,
    const int* __restrict__ flags, int N) {
  __shared__ unsigned short hs[64][264];
  const bool f32 = flags[0] != 0;
  const int tid = threadIdx.x, lane = tid & 63, wid = tid >> 6;
  const int l15 = lane & 15, quad = lane >> 4;
  const int base = blockIdx.x * 64;
  int mn = min(base + wid * 16 + l15, N - 1);

  f32x4 zero = {0.f, 0.f, 0.f, 0.f};
  f32x4 acca[8], accb[8];
#pragma unroll
  for (int ct = 0; ct < 8; ct++) { acca[ct] = zero; accb[ct] = zero; }
#pragma unroll
  for (int ks = 0; ks < 4; ks++) {
    short8 a = load_a8(x, (size_t)mn, ks * 32 + quad * 8, f32);
    const unsigned short* wpa = P1 + ((size_t)(ks * 8) * 64 + lane) * 8;
    const unsigned short* wpb = P1 + ((size_t)((ks + 4) * 8) * 64 + lane) * 8;
#pragma unroll
    for (int ct = 0; ct < 8; ct++) {
      short8 ba = *(const short8*)(wpa + ct * 512);
      short8 bb = *(const short8*)(wpb + ct * 512);
      acca[ct] = __builtin_amdgcn_mfma_f32_16x16x32_bf16(a, ba, acca[ct], 0, 0, 0);
      accb[ct] = __builtin_amdgcn_mfma_f32_16x16x32_bf16(a, bb, accb[ct], 0, 0, 0);
    }
  }
#pragma unroll
  for (int ct = 0; ct < 8; ct++) {
    const int col = ct * 16 + l15;
    const float bv = loads(b1, col, f32);
#pragma unroll
    for (int r = 0; r < 4; r++) {
      hs[wid * 16 + quad * 4 + r][col]       = f2bf(acca[ct][r] + bv);
      hs[wid * 16 + quad * 4 + r][128 + col] = f2bf(accb[ct][r]);
    }
  }
  __syncthreads();
  const int row = tid >> 2, part = tid & 3;
  if (base + row < N) {
    unsigned short* op = X1 + (size_t)(base + row) * 256 + part * 64;
#pragma unroll
    for (int j = 0; j < 8; j++)
      *(short8*)(op + j * 8) = *(const short8*)&hs[row][part * 64 + j * 8];
  }
}

// ---------------------------------------------------------------------------
// edgeS: per 64 SORTED edges (by dst): eattr[perm[e]]@W1c -> +X1a[src]+X1b[dst]
// relu -> @W2 + b2 -> fp32 messages in LDS -> in-block segmented reduce by dst
// -> boundary atomics into aggf.  Messages never touch HBM.
// ---------------------------------------------------------------------------
__global__ __launch_bounds__(256) void edgeS_kernel(
    const void* __restrict__ eattr, const int* __restrict__ ssrc,
    const int* __restrict__ sdst, const int* __restrict__ perm,
    const unsigned short* __restrict__ X1,
    const unsigned short* __restrict__ P1, const unsigned short* __restrict__ P2,
    const void* __restrict__ b2, float* __restrict__ aggf,
    const int* __restrict__ flags, int E, int N) {
  __shared__ __align__(16) char smem[64 * 132 * 4];   // hs (bf16) unioned with ms (fp32)
  __shared__ int sdst_s[64], ssrc_s[64];
  unsigned short (*hs)[136] = (unsigned short (*)[136])smem;
  float (*ms)[132] = (float (*)[132])smem;
  const bool f32 = flags[0] != 0;
  const int tid = threadIdx.x, lane = tid & 63, wid = tid >> 6;
  const int l15 = lane & 15, quad = lane >> 4;
  const int base = blockIdx.x * 64;

  if (tid < 64) {
    int e = min(base + tid, E - 1);
    sdst_s[tid] = sdst[e];
    ssrc_s[tid] = ssrc[e];
  }

  const int me = min(base + wid * 16 + l15, E - 1);
  const int pe = perm[me];

  // GEMM1: eattr[pe] @ W1c  (W1 rows 256..383 = P1 ks 8..11)
  f32x4 zero = {0.f, 0.f, 0.f, 0.f};
  f32x4 acc[8];
#pragma unroll
  for (int ct = 0; ct < 8; ct++) acc[ct] = zero;
#pragma unroll
  for (int ks = 0; ks < 4; ks++) {
    short8 a = load_a8(eattr, (size_t)pe, ks * 32 + quad * 8, f32);
    const unsigned short* wp = P1 + ((size_t)((ks + 8) * 8) * 64 + lane) * 8;
#pragma unroll
    for (int ct = 0; ct < 8; ct++) {
      short8 b = *(const short8*)(wp + ct * 512);
      acc[ct] = __builtin_amdgcn_mfma_f32_16x16x32_bf16(a, b, acc[ct], 0, 0, 0);
    }
  }
#pragma unroll
  for (int ct = 0; ct < 8; ct++) {
    const int col = ct * 16 + l15;
#pragma unroll
    for (int r = 0; r < 4; r++)
      hsb_write: ;
  }
#pragma unroll
  for (int ct = 0; ct < 8; ct++) {
    const int col = ct * 16 + l15;
#pragma unroll
    for (int r = 0; r < 4; r++)
      hs[wid * 16 + quad * 4 + r][col] = f2bf(acc[ct][r]);
  }
  __syncthreads();  // publishes ssrc_s/sdst_s (hs rows stay wave-private)

  // Add X1a[src] + X1b[dst], ReLU — wave-private rows (wid*16 + lane/4),
  // 4 lanes per row reading contiguous 64 B chunks (coalesced-within-row).
  {
    const int r = wid * 16 + (lane >> 2);
    const int cq = (lane & 3) * 8;          // 16 B sub-chunk
    const int s = ssrc_s[r], d = sdst_s[r];
    const unsigned short* ap = X1 + (size_t)s * 256;
    const unsigned short* bp = X1 + (size_t)d * 256 + 128;
#pragma unroll
    for (int j = 0; j < 4; j++) {
      const int c0 = cq + j * 32;
      short8 h8 = *(const short8*)&hs[r][c0];
      short8 a8 = *(const short8*)(ap + c0);
      short8 b8 = *(const short8*)(bp + c0);
      short8 o;
#pragma unroll
      for (int k = 0; k < 8; k++) {
        float v = bf2f((unsigned short)h8[k]) + bf2f((unsigned short)a8[k])
                + bf2f((unsigned short)b8[k]);
        o[k] = (short)f2bf(fmaxf(v, 0.f));
      }
      *(short8*)&hs[r][c0] = o;
    }
  }

  // GEMM2: h @ W2 (wave-private rows, no barrier needed since add was same-wave).
  f32x4 acc2[8];
#pragma unroll
  for (int ct = 0; ct < 8; ct++) acc2[ct] = zero;
#pragma unroll
  for (int ks = 0; ks < 4; ks++) {
    short8 a = *(const short8*)&hs[wid * 16 + l15][ks * 32 + quad * 8];
    const unsigned short* wp = P2 + ((size_t)(ks * 8) * 64 + lane) * 8;
#pragma unroll
    for (int ct = 0; ct < 8; ct++) {
      short8 b = *(const short8*)(wp + ct * 512);
      acc2[ct] = __builtin_amdgcn_mfma_f32_16x16x32_bf16(a, b, acc2[ct], 0, 0, 0);
    }
  }
  float b2v[8];
#pragma unroll
  for (int ct = 0; ct < 8; ct++) b2v[ct] = loads(b2, ct * 16 + l15, f32);
  __syncthreads();  // all hs reads complete before ms overwrites the buffer
#pragma unroll
  for (int ct = 0; ct < 8; ct++) {
    const int col = ct * 16 + l15;
#pragma unroll
    for (int r = 0; r < 4; r++) {
      const int e = base + wid * 16 + quad * 4 + r;
      ms[wid * 16 + quad * 4 + r][col] = (e < E) ? (acc2[ct][r] + b2v[ct]) : 0.0f;
    }
  }
  __syncthreads();

  // Segmented reduce over sorted dst: 2 threads per column, 32 rows each.
  const int col  = tid & 127;
  const int half = tid >> 7;
  const int r0 = half * 32;
  float sum = 0.0f;
  int cur = sdst_s[r0];
#pragma unroll 4
  for (int r = r0; r < r0 + 32; r++) {
    int d = sdst_s[r];
    if (d != cur) {
      atomicAdd(&aggf[(size_t)cur * HID + col], sum);
      sum = 0.0f; cur = d;
    }
    sum += ms[r][col];
  }
  atomicAdd(&aggf[(size_t)cur * HID + col], sum);
}

// ---------------------------------------------------------------------------
// Mode-2 fallback kernels (round-3 structure, kept intact).
// ---------------------------------------------------------------------------
__global__ __launch_bounds__(1024) void scan_kernel(const int* __restrict__ counts,
                                                    int* __restrict__ offs, int N) {
  __shared__ int wsum[16];
  __shared__ int wpre[16];
  __shared__ int carry_s;
  const int tid = threadIdx.x, lane = tid & 63, wid = tid >> 6;
  if (tid == 0) carry_s = 0;
  __syncthreads();
  for (int base = 0; base < N; base += 1024) {
    int i = base + tid;
    int v = (i < N) ? counts[i] : 0;
    int s = v;
#pragma unroll
    for (int off = 1; off < 64; off <<= 1) {
      int t = __shfl_up(s, off, 64);
      if (lane >= off) s += t;
    }
    if (lane == 63) wsum[wid] = s;
    __syncthreads();
    if (tid == 0) {
      int run = carry_s;
#pragma unroll
      for (int w = 0; w < 16; w++) { int t = wsum[w]; wpre[w] = run; run += t; }
      carry_s = run;
    }
    __syncthreads();
    if (i < N) offs[i] = wpre[wid] + s - v;
    __syncthreads();
  }
  if (tid == 0) offs[N] = carry_s;
}

__global__ void scatter_kernel(const int* __restrict__ eidx, int* __restrict__ cur,
                               int* __restrict__ ssrc, int* __restrict__ sdst,
                               int* __restrict__ perm,
                               const int* __restrict__ flags, int E, int N) {
  const bool i64 = flags[1] != 0;
  int e = blockIdx.x * 256 + threadIdx.x;
  if (e < E) {
    int d = get_dst(eidx, i64, E, e);
    int s = get_src(eidx, i64, E, e);
    d = min(max(d, 0), N - 1);
    s = min(max(s, 0), N - 1);
    int pos = atomicAdd(&cur[d], 1);
    ssrc[pos] = s;
    sdst[pos] = d;
    perm[pos] = e;
  }
}

__global__ __launch_bounds__(256) void edge_kernel_sorted(
    const void* __restrict__ x, const void* __restrict__ eattr,
    const int* __restrict__ ssrc, const int* __restrict__ sdst,
    const int* __restrict__ perm,
    const unsigned short* __restrict__ P1, const void* __restrict__ b1,
    const unsigned short* __restrict__ P2, const void* __restrict__ b2,
    float* __restrict__ aggf, const int* __restrict__ flags, int E, int N) {
  __shared__ __align__(16) char smem[64 * 132 * 4];
  __shared__ int sdst_s[64];
  unsigned short (*hs)[136] = (unsigned short (*)[136])smem;
  float (*ms)[132] = (float (*)[132])smem;
  const bool f32 = flags[0] != 0;
  const int tid = threadIdx.x, lane = tid & 63, wid = tid >> 6;
  const int l15 = lane & 15, quad = lane >> 4;
  const int base = blockIdx.x * 64;

  if (tid < 64) sdst_s[tid] = sdst[min(base + tid, E - 1)];

  int me = base + wid * 16 + l15;
  if (me >= E) me = E - 1;
  const int src = ssrc[me];
  const int dsm = sdst[me];
  const int pe  = perm[me];

  f32x4 zero = {0.f, 0.f, 0.f, 0.f};
  f32x4 acc[8];
#pragma unroll
  for (int ct = 0; ct < 8; ct++) acc[ct] = zero;
#pragma unroll
  for (int ks = 0; ks < 12; ks++) {
    const int k0 = ks * 32;
    short8 a;
    if (k0 < 128)      a = load_a8(x,     (size_t)src, k0 + quad * 8, f32);
    else if (k0 < 256) a = load_a8(x,     (size_t)dsm, (k0 - 128) + quad * 8, f32);
    else               a = load_a8(eattr, (size_t)pe,  (k0 - 256) + quad * 8, f32);
    const unsigned short* wp = P1 + ((size_t)(ks * 8) * 64 + lane) * 8;
#pragma unroll
    for (int ct = 0; ct < 8; ct++) {
      short8 b = *(const short8*)(wp + ct * 512);
      acc[ct] = __builtin_amdgcn_mfma_f32_16x16x32_bf16(a, b, acc[ct], 0, 0, 0);
    }
  }
#pragma unroll
  for (int ct = 0; ct < 8; ct++) {
    const int col = ct * 16 + l15;
    const float bv = loads(b1, col, f32);
#pragma unroll
    for (int r = 0; r < 4; r++)
      hs[wid * 16 + quad * 4 + r][col] = f2bf(fmaxf(acc[ct][r] + bv, 0.f));
  }
  f32x4 acc2[8];
#pragma unroll
  for (int ct = 0; ct < 8; ct++) acc2[ct] = zero;
#pragma unroll
  for (int ks = 0; ks < 4; ks++) {
    short8 a = *(const short8*)&hs[wid * 16 + l15][ks * 32 + quad * 8];
    const unsigned short* wp = P2 + ((size_t)(ks * 8) * 64 + lane) * 8;
#pragma unroll
    for (int ct = 0; ct < 8; ct++) {
      short8 b = *(const short8*)(wp + ct * 512);
      acc2[ct] = __builtin_amdgcn_mfma_f32_16x16x32_bf16(a, b, acc2[ct], 0, 0, 0);
    }
  }
  float b2v[8];
#pragma unroll
  for (int ct = 0; ct < 8; ct++) b2v[ct] = loads(b2, ct * 16 + l15, f32);
  __syncthreads();
#pragma unroll
  for (int ct = 0; ct < 8; ct++) {
    const int col = ct * 16 + l15;
#pragma unroll
    for (int r = 0; r < 4; r++) {
      const int e = base + wid * 16 + quad * 4 + r;
      ms[wid * 16 + quad * 4 + r][col] = (e < E) ? (acc2[ct][r] + b2v[ct]) : 0.0f;
    }
  }
  __syncthreads();
  const int col  = tid & 127;
  const int half = tid >> 7;
  const int r0 = half * 32;
  float sum = 0.0f;
  int cur = sdst_s[r0];
#pragma unroll 4
  for (int r = r0; r < r0 + 32; r++) {
    int d = sdst_s[r];
    if (d != cur) {
      atomicAdd(&aggf[(size_t)cur * HID + col], sum);
      sum = 0.0f; cur = d;
    }
    sum += ms[r][col];
  }
  atomicAdd(&aggf[(size_t)cur * HID + col], sum);
}

__global__ __launch_bounds__(256) void edge_kernel_plain(
    const void* __restrict__ x, const int* __restrict__ eidx,
    const void* __restrict__ eattr,
    const unsigned short* __restrict__ P1, const void* __restrict__ b1,
    const unsigned short* __restrict__ P2, const void* __restrict__ b2,
    float* __restrict__ aggf, void* __restrict__ out,
    const int* __restrict__ flags, int E, int N, int small_mode) {
  __shared__ unsigned short hs[64][136];
  const bool f32 = flags[0] != 0;
  const bool i64 = flags[1] != 0;
  const int tid = threadIdx.x, lane = tid & 63, wid = tid >> 6;
  const int l15 = lane & 15, quad = lane >> 4;
  const int base = blockIdx.x * 64;

  int me = base + wid * 16 + l15;
  if (me >= E) me = E - 1;
  int src = get_src(eidx, i64, E, me);
  int dsm = get_dst(eidx, i64, E, me);
  src = min(max(src, 0), N - 1);
  dsm = min(max(dsm, 0), N - 1);

  f32x4 zero = {0.f, 0.f, 0.f, 0.f};
  f32x4 acc[8];
#pragma unroll
  for (int ct = 0; ct < 8; ct++) acc[ct] = zero;
#pragma unroll
  for (int ks = 0; ks < 12; ks++) {
    const int k0 = ks * 32;
    short8 a;
    if (k0 < 128)      a = load_a8(x,     (size_t)src, k0 + quad * 8, f32);
    else if (k0 < 256) a = load_a8(x,     (size_t)dsm, (k0 - 128) + quad * 8, f32);
    else               a = load_a8(eattr, (size_t)me,  (k0 - 256) + quad * 8, f32);
    const unsigned short* wp = P1 + ((size_t)(ks * 8) * 64 + lane) * 8;
#pragma unroll
    for (int ct = 0; ct < 8; ct++) {
      short8 b = *(const short8*)(wp + ct * 512);
      acc[ct] = __builtin_amdgcn_mfma_f32_16x16x32_bf16(a, b, acc[ct], 0, 0, 0);
    }
  }
#pragma unroll
  for (int ct = 0; ct < 8; ct++) {
    const int col = ct * 16 + l15;
    const float bv = loads(b1, col, f32);
#pragma unroll
    for (int r = 0; r < 4; r++)
      hs[wid * 16 + quad * 4 + r][col] = f2bf(fmaxf(acc[ct][r] + bv, 0.f));
  }
  __syncthreads();
  f32x4 acc2[8];
#pragma unroll
  for (int ct = 0; ct < 8; ct++) acc2[ct] = zero;
#pragma unroll
  for (int ks = 0; ks < 4; ks++) {
    short8 a = *(const short8*)&hs[wid * 16 + l15][ks * 32 + quad * 8];
    const unsigned short* wp = P2 + ((size_t)(ks * 8) * 64 + lane) * 8;
#pragma unroll
    for (int ct = 0; ct < 8; ct++) {
      short8 b = *(const short8*)(wp + ct * 512);
      acc2[ct] = __builtin_amdgcn_mfma_f32_16x16x32_bf16(a, b, acc2[ct], 0, 0, 0);
    }
  }
  float b2v[8];
#pragma unroll
  for (int ct = 0; ct < 8; ct++) b2v[ct] = loads(b2, ct * 16 + l15, f32);

  if (!small_mode || f32) {
    float* tgt = (!small_mode) ? aggf : (float*)out;
#pragma unroll
    for (int r = 0; r < 4; r++) {
      const int e = base + wid * 16 + quad * 4 + r;
      if (e < E) {
        int d = get_dst(eidx, i64, E, e);
        d = min(max(d, 0), N - 1);
        float* op = tgt + (size_t)d * HID + l15;
#pragma unroll
        for (int ct = 0; ct < 8; ct++) atomicAdd(op + ct * 16, acc2[ct][r] + b2v[ct]);
      }
    }
  } else {
#pragma unroll
    for (int ct = 0; ct < 8; ct++) {
      const int col = ct * 16 + l15;
#pragma unroll
      for (int r = 0; r < 4; r++)
        hs[wid * 16 + quad * 4 + r][col] = f2bf(acc2[ct][r] + b2v[ct]);
    }
    __syncthreads();
    const int row = tid >> 2;
    const int cg  = (tid & 3) * 32;
    const int e = base + row;
    if (e < E) {
      int d = get_dst(eidx, i64, E, e);
      d = min(max(d, 0), N - 1);
      unsigned int* orow = (unsigned int*)out + ((size_t)d * HID >> 1);
#pragma unroll
      for (int p = 0; p < 16; p++) {
        const int col = cg + p * 2;
        const float lo = bf2f(hs[row][col]);
        const float hi = bf2f(hs[row][col + 1]);
        unsigned int* wp = orow + (col >> 1);
        unsigned int old = *wp, assumed;
        do {
          assumed = old;
          unsigned int nv = (unsigned int)f2bf(bf2f((unsigned short)(assumed & 0xFFFF)) + lo)
                          | ((unsigned int)f2bf(bf2f((unsigned short)(assumed >> 16)) + hi) << 16);
          old = atomicCAS(wp, assumed, nv);
        } while (old != assumed);
      }
    }
  }
}

// ---------------------------------------------------------------------------
// Node kernel: u = relu([x|agg]@U1+ub1); upd = u@U2+ub2; out = LN(x+upd)*g+b
// ---------------------------------------------------------------------------
__global__ __launch_bounds__(256) void node_kernel(
    const void* __restrict__ x, const float* __restrict__ aggf,
    const unsigned short* __restrict__ PU1, const void* __restrict__ ub1,
    const unsigned short* __restrict__ PU2, const void* __restrict__ ub2,
    const void* __restrict__ gamma, const void* __restrict__ beta,
    void* __restrict__ out, const int* __restrict__ flags, int N, int small_mode) {
  __shared__ unsigned short hs[64][136];
  const bool f32 = flags[0] != 0;
  const int tid = threadIdx.x, lane = tid & 63, wid = tid >> 6;
  const int l15 = lane & 15, quad = lane >> 4;
  const int base = blockIdx.x * 64;

  int mn = base + wid * 16 + l15;
  if (mn >= N) mn = N - 1;

  const void* aggp = (!small_mode) ? (const void*)aggf : (const void*)out;
  const bool aggF32 = (!small_mode) ? true : f32;

  f32x4 zero = {0.f, 0.f, 0.f, 0.f};
  f32x4 acc[8];
#pragma unroll
  for (int ct = 0; ct < 8; ct++) acc[ct] = zero;
#pragma unroll
  for (int ks = 0; ks < 8; ks++) {
    const int k0 = ks * 32;
    short8 a;
    if (k0 < 128) a = load_a8(x,    (size_t)mn, k0 + quad * 8, f32);
    else          a = load_a8(aggp, (size_t)mn, (k0 - 128) + quad * 8, aggF32);
    const unsigned short* wp = PU1 + ((size_t)(ks * 8) * 64 + lane) * 8;
#pragma unroll
    for (int ct = 0; ct < 8; ct++) {
      short8 b = *(const short8*)(wp + ct * 512);
      acc[ct] = __builtin_amdgcn_mfma_f32_16x16x32_bf16(a, b, acc[ct], 0, 0, 0);
    }
  }
#pragma unroll
  for (int ct = 0; ct < 8; ct++) {
    const int col = ct * 16 + l15;
    const float bv = loads(ub1, col, f32);
#pragma unroll
    for (int r = 0; r < 4; r++)
      hs[wid * 16 + quad * 4 + r][col] = f2bf(fmaxf(acc[ct][r] + bv, 0.f));
  }
  __syncthreads();
  f32x4 acc2[8];
#pragma unroll
  for (int ct = 0; ct < 8; ct++) acc2[ct] = zero;
#pragma unroll
  for (int ks = 0; ks < 4; ks++) {
    short8 a = *(const short8*)&hs[wid * 16 + l15][ks * 32 + quad * 8];
    const unsigned short* wp = PU2 + ((size_t)(ks * 8) * 64 + lane) * 8;
#pragma unroll
    for (int ct = 0; ct < 8; ct++) {
      short8 b = *(const short8*)(wp + ct * 512);
      acc2[ct] = __builtin_amdgcn_mfma_f32_16x16x32_bf16(a, b, acc2[ct], 0, 0, 0);
    }
  }

  float vals[8][4];
  float s1[4] = {0.f, 0.f, 0.f, 0.f};
  float s2[4] = {0.f, 0.f, 0.f, 0.f};
#pragma unroll
  for (int ct = 0; ct < 8; ct++) {
    const int col = ct * 16 + l15;
    const float bv = loads(ub2, col, f32);
#pragma unroll
    for (int r = 0; r < 4; r++) {
      int row = base + wid * 16 + quad * 4 + r;
      int rc = row < N ? row : 0;
      float v = acc2[ct][r] + bv + loads(x, (size_t)rc * HID + col, f32);
      vals[ct][r] = v;
      s1[r] += v;
      s2[r] += v * v;
    }
  }
#pragma unroll
  for (int off = 1; off < 16; off <<= 1) {
#pragma unroll
    for (int r = 0; r < 4; r++) {
      s1[r] += __shfl_xor(s1[r], off, 16);
      s2[r] += __shfl_xor(s2[r], off, 16);
    }
  }
#pragma unroll
  for (int r = 0; r < 4; r++) {
    const int row = base + wid * 16 + quad * 4 + r;
    if (row < N) {
      const float mean = s1[r] * (1.0f / 128.0f);
      const float var  = fmaxf(s2[r] * (1.0f / 128.0f) - mean * mean, 0.0f);
      const float rstd = rsqrtf(var + 1e-5f);
#pragma unroll
      for (int ct = 0; ct < 8; ct++) {
        const int col = ct * 16 + l15;
        float o = (vals[ct][r] - mean) * rstd * loads(gamma, col, f32) + loads(beta, col, f32);
        if (f32) ((float*)out)[(size_t)row * HID + col] = o;
        else     ((unsigned short*)out)[(size_t)row * HID + col] = f2bf(o);
      }
    }
  }
}

// ---------------------------------------------------------------------------
extern "C" void kernel_launch(void* const* d_in, const int* in_sizes, int n_in,
                              void* d_out, int out_size, void* d_ws, size_t ws_size,
                              hipStream_t stream) {
  (void)n_in;
  const void* x     = d_in[0];
  const int*  eidx  = (const int*)d_in[1];
  const void* eattr = d_in[2];
  const void* W1  = d_in[3];
  const void* b1  = d_in[4];
  const void* W2  = d_in[5];
  const void* b2  = d_in[6];
  const void* U1  = d_in[7];
  const void* ub1 = d_in[8];
  const void* U2  = d_in[9];
  const void* ub2 = d_in[10];
  const void* gam = d_in[11];
  const void* bet = d_in[12];

  const int N = in_sizes[0] / HID;
  const int E = in_sizes[2] / HID;

  char* ws = (char*)d_ws;
  auto alignup = [](size_t v) { return (v + 255) & ~(size_t)255; };

  int* flags = (int*)ws;                                       // 256 B
  unsigned short* P1  = (unsigned short*)(ws + 256);
  unsigned short* P2  = (unsigned short*)(ws + 256 + 98304);
  unsigned short* PU1 = (unsigned short*)(ws + 256 + 131072);
  unsigned short* PU2 = (unsigned short*)(ws + 256 + 196608);
  const size_t agg_off = 256 + 229376;
  float* aggf = (float*)(ws + agg_off);
  const size_t agg_bytes = (size_t)N * HID * sizeof(float);
  const size_t need_basic = agg_off + agg_bytes;

  // ---- mode-3 layout: sort + X1 precompute + fused sorted edge kernel ----
  size_t o3 = alignup(need_basic);
  size_t cnt_off  = o3; o3 = alignup(o3 + (size_t)(N + 64) * 4);
  size_t cur_off  = o3; o3 = alignup(o3 + (size_t)(N + 64) * 4);
  size_t bsum_off = o3; o3 = alignup(o3 + 1024);
  size_t src3_off = o3; o3 = alignup(o3 + (size_t)E * 4);
  size_t dst3_off = o3; o3 = alignup(o3 + (size_t)E * 4);
  size_t prm3_off = o3; o3 = alignup(o3 + (size_t)E * 4);
  size_t x1_off   = o3; o3 = alignup(o3 + (size_t)N * 256 * 2);
  const size_t need3 = o3;

  // ---- mode-2 layout (round-3) ----
  size_t o2 = alignup(need_basic);
  size_t offs_off = o2; o2 = alignup(o2 + (size_t)(N + 1) * 4);
  size_t cur2_off = o2; o2 = alignup(o2 + (size_t)(N + 1) * 4);
  size_t ssrc_off = o2; o2 = alignup(o2 + (size_t)E * 4);
  size_t sds2_off = o2; o2 = alignup(o2 + (size_t)E * 4);
  size_t perm_off = o2; o2 = alignup(o2 + (size_t)E * 4);
  const size_t need2 = o2;

  const int mode = (ws_size >= need3) ? 3
                 : (ws_size >= need2) ? 2
                 : (ws_size >= need_basic) ? 1 : 0;

  detect_kernel<<<1, 256, 0, stream>>>(x, eidx, flags);
  repack_all<<<448, 256, 0, stream>>>(W1, W2, U1, U2, P1, P2, PU1, PU2, flags);

  if (mode == 3) {
    int* cntb = (int*)(ws + cnt_off);
    int* curb = (int*)(ws + cur_off);
    int* bsum = (int*)(ws + bsum_off);
    int* ssrc = (int*)(ws + src3_off);
    int* sdst = (int*)(ws + dst3_off);
    int* perm = (int*)(ws + prm3_off);
    unsigned short* X1 = (unsigned short*)(ws + x1_off);
    const int nb = (N + 1023) / 1024;

    hipMemsetAsync(aggf, 0, agg_bytes, stream);
    hipMemsetAsync(cntb, 0, (size_t)N * 4, stream);
    hist_kernel<<<(E + 255) / 256, 256, 0, stream>>>(eidx, cntb, flags, E, N);
    scanA_kernel<<<nb, 1024, 0, stream>>>(cntb, curb, bsum, N);
    scanB_kernel<<<1, 64, 0, stream>>>(bsum, nb);
    scanC_kernel<<<nb, 1024, 0, stream>>>(curb, bsum, N);
    scatter_kernel<<<(E + 255) / 256, 256, 0, stream>>>(eidx, curb, ssrc, sdst, perm,
                                                        flags, E, N);
    x1_kernel<<<(N + 63) / 64, 256, 0, stream>>>(x, P1, b1, X1, flags, N);
    edgeS_kernel<<<(E + 63) / 64, 256, 0, stream>>>(eattr, ssrc, sdst, perm, X1,
                                                    P1, P2, b2, aggf, flags, E, N);
    node_kernel<<<(N + 63) / 64, 256, 0, stream>>>(x, aggf, PU1, ub1, PU2, ub2,
                                                   gam, bet, d_out, flags, N, 0);
  } else if (mode == 2) {
    int* offsb = (int*)(ws + offs_off);
    int* curb  = (int*)(ws + cur2_off);
    int* ssrc  = (int*)(ws + ssrc_off);
    int* sdst  = (int*)(ws + sds2_off);
    int* perm  = (int*)(ws + perm_off);
    hipMemsetAsync(aggf, 0, agg_bytes, stream);
    hipMemsetAsync(curb, 0, (size_t)(N + 1) * 4, stream);
    hist_kernel<<<(E + 255) / 256, 256, 0, stream>>>(eidx, curb, flags, E, N);
    scan_kernel<<<1, 1024, 0, stream>>>(curb, offsb, N);
    hipMemcpyAsync(curb, offsb, (size_t)(N + 1) * 4, hipMemcpyDeviceToDevice, stream);
    scatter_kernel<<<(E + 255) / 256, 256, 0, stream>>>(eidx, curb, ssrc, sdst, perm,
                                                        flags, E, N);
    edge_kernel_sorted<<<(E + 63) / 64, 256, 0, stream>>>(x, eattr, ssrc, sdst, perm,
                                                          P1, b1, P2, b2, aggf, flags, E, N);
    node_kernel<<<(N + 63) / 64, 256, 0, stream>>>(x, aggf, PU1, ub1, PU2, ub2,
                                                   gam, bet, d_out, flags, N, 0);
  } else if (mode == 1) {
    hipMemsetAsync(aggf, 0, agg_bytes, stream);
    edge_kernel_plain<<<(E + 63) / 64, 256, 0, stream>>>(x, eidx, eattr, P1, b1, P2, b2,
                                                         aggf, d_out, flags, E, N, 0);
    node_kernel<<<(N + 63) / 64, 256, 0, stream>>>(x, aggf, PU1, ub1, PU2, ub2,
                                                   gam, bet, d_out, flags, N, 0);
  } else {
    zero_out_kernel<<<1024, 256, 0, stream>>>((unsigned int*)d_out, flags, (long long)out_size);
    edge_kernel_plain<<<(E + 63) / 64, 256, 0, stream>>>(x, eidx, eattr, P1, b1, P2, b2,
                                                         aggf, d_out, flags, E, N, 1);
    node_kernel<<<(N + 63) / 64, 256, 0, stream>>>(x, aggf, PU1, ub1, PU2, ub2,
                                                   gam, bet, d_out, flags, N, 1);
  }
}

// Round 5
// 758.675 us; speedup vs baseline: 1.1551x; 1.0324x over previous
//
#include <hip/hip_runtime.h>

#define HID 128

typedef __attribute__((ext_vector_type(8))) short short8;
typedef __attribute__((ext_vector_type(4))) float f32x4;
typedef __attribute__((ext_vector_type(2))) float f32x2;

__device__ __forceinline__ float bf2f(unsigned short u) {
  union { unsigned int u; float f; } c; c.u = ((unsigned int)u) << 16; return c.f;
}
__device__ __forceinline__ unsigned short f2bf(float f) {
  union { float f; unsigned int u; } c; c.f = f;
  unsigned int u = c.u;
  return (unsigned short)((u + 0x7FFFu + ((u >> 16) & 1u)) >> 16);  // RNE
}
__device__ __forceinline__ float loads(const void* p, size_t i, bool f32) {
  return f32 ? ((const float*)p)[i] : bf2f(((const unsigned short*)p)[i]);
}
__device__ __forceinline__ short8 load_a8(const void* base, size_t row, int k, bool f32) {
  if (!f32) return *(const short8*)((const unsigned short*)base + row * HID + k);
  const float* fp = (const float*)base + row * HID + k;
  f32x4 f0 = *(const f32x4*)fp;
  f32x4 f1 = *(const f32x4*)(fp + 4);
  short8 t;
  t[0] = (short)f2bf(f0[0]); t[1] = (short)f2bf(f0[1]);
  t[2] = (short)f2bf(f0[2]); t[3] = (short)f2bf(f0[3]);
  t[4] = (short)f2bf(f1[0]); t[5] = (short)f2bf(f1[1]);
  t[6] = (short)f2bf(f1[2]); t[7] = (short)f2bf(f1[3]);
  return t;
}

// ---------------------------------------------------------------------------
// Runtime dtype detection. flags[0]=1 -> fp32 floats; flags[1]=1 -> int64 idx.
// ---------------------------------------------------------------------------
__global__ void detect_kernel(const void* __restrict__ x,
                              const int* __restrict__ eidx,
                              int* __restrict__ flags) {
  __shared__ int bad, oddnz;
  if (threadIdx.x == 0) { bad = 0; oddnz = 0; }
  __syncthreads();
  const unsigned short* xu = (const unsigned short*)x;
  int mybad = 0;
  for (int i = threadIdx.x; i < 4096; i += 256) {
    int ef = (xu[i] >> 7) & 0xFF;
    if (!(ef == 0 || (ef >= 90 && ef <= 140))) mybad++;
  }
  if (mybad) atomicAdd(&bad, mybad);
  if (threadIdx.x < 128) {
    if (eidx[2 * threadIdx.x + 1] != 0) atomicAdd(&oddnz, 1);
  }
  __syncthreads();
  if (threadIdx.x == 0) {
    flags[0] = (bad > 409) ? 1 : 0;
    flags[1] = (oddnz == 0) ? 1 : 0;
  }
}

__device__ __forceinline__ int get_dst(const int* eidx, bool i64, int E, int e) {
  return i64 ? eidx[2 * (E + e)] : eidx[E + e];
}
__device__ __forceinline__ int get_src(const int* eidx, bool i64, int E, int e) {
  return i64 ? eidx[2 * e] : eidx[e];
}

__global__ void zero_out_kernel(unsigned int* __restrict__ out,
                                const int* __restrict__ flags, long long nelem) {
  bool f32 = flags[0] != 0;
  size_t words = (size_t)nelem * (f32 ? 2 : 1) / 2;
  for (size_t w = blockIdx.x * 256ull + threadIdx.x; w < words; w += (size_t)gridDim.x * 256ull)
    out[w] = 0u;
}

// ---------------------------------------------------------------------------
// Repack weights into MFMA B-fragment order (bf16).
// ---------------------------------------------------------------------------
__global__ void repack_all(const void* __restrict__ W1, const void* __restrict__ W2,
                           const void* __restrict__ U1, const void* __restrict__ U2,
                           unsigned short* __restrict__ P1, unsigned short* __restrict__ P2,
                           unsigned short* __restrict__ PU1, unsigned short* __restrict__ PU2,
                           const int* __restrict__ flags) {
  const bool f32 = flags[0] != 0;
  int idx = blockIdx.x * 256 + threadIdx.x;
  const int s1 = 384 * 128, s2 = s1 + 128 * 128, s3 = s2 + 256 * 128, s4 = s3 + 128 * 128;
  if (idx >= s4) return;
  const void* W; unsigned short* P; int off;
  if (idx < s1)      { W = W1; P = P1;  off = idx; }
  else if (idx < s2) { W = W2; P = P2;  off = idx - s1; }
  else if (idx < s3) { W = U1; P = PU1; off = idx - s2; }
  else               { W = U2; P = PU2; off = idx - s3; }
  int j = off & 7, lane = (off >> 3) & 63, ct = (off >> 9) & 7, ks = off >> 12;
  int k = ks * 32 + ((lane >> 4) << 3) + j;
  int n = ct * 16 + (lane & 15);
  P[off] = f2bf(loads(W, (size_t)k * 128 + n, f32));
}

// ---------------------------------------------------------------------------
// Sort machinery: histogram, multi-block 3-phase scan, scatter.
// ---------------------------------------------------------------------------
__global__ void hist_kernel(const int* __restrict__ eidx, int* __restrict__ counts,
                            const int* __restrict__ flags, int E, int N) {
  const bool i64 = flags[1] != 0;
  int e = blockIdx.x * 256 + threadIdx.x;
  if (e < E) {
    int d = get_dst(eidx, i64, E, e);
    d = min(max(d, 0), N - 1);
    atomicAdd(&counts[d], 1);
  }
}

// Phase A: per-1024-block exclusive scan -> curb; block totals -> bsum.
__global__ __launch_bounds__(1024) void scanA_kernel(const int* __restrict__ cnt,
                                                     int* __restrict__ curb,
                                                     int* __restrict__ bsum, int N) {
  __shared__ int wsum[16], wsum2[16];
  const int tid = threadIdx.x, lane = tid & 63, wid = tid >> 6;
  int i = blockIdx.x * 1024 + tid;
  int v = (i < N) ? cnt[i] : 0;
  int s = v;
#pragma unroll
  for (int off = 1; off < 64; off <<= 1) {
    int t = __shfl_up(s, off, 64);
    if (lane >= off) s += t;
  }
  if (lane == 63) wsum[wid] = s;
  __syncthreads();
  if (wid == 0 && lane < 16) {
    int w = wsum[lane];
#pragma unroll
    for (int off = 1; off < 16; off <<= 1) {
      int t = __shfl_up(w, off, 16);
      if (lane >= off) w += t;
    }
    wsum2[lane] = w;
    if (lane == 15) bsum[blockIdx.x] = w;
  }
  __syncthreads();
  int pre = (wid > 0) ? wsum2[wid - 1] : 0;
  if (i < N) curb[i] = pre + s - v;
}

// Phase B: serial exclusive scan of block sums (nb small).
__global__ void scanB_kernel(int* __restrict__ bsum, int nb) {
  if (threadIdx.x == 0 && blockIdx.x == 0) {
    int run = 0;
    for (int b = 0; b < nb; b++) { int t = bsum[b]; bsum[b] = run; run += t; }
  }
}

// Phase C: add block offsets.
__global__ __launch_bounds__(1024) void scanC_kernel(int* __restrict__ curb,
                                                     const int* __restrict__ bsum, int N) {
  int i = blockIdx.x * 1024 + threadIdx.x;
  if (i < N) curb[i] += bsum[blockIdx.x];
}

// ---------------------------------------------------------------------------
// x1_kernel: X1[n] = [ x[n]@W1a + b1 | x[n]@W1b ]  (bf16, N x 256)
// ---------------------------------------------------------------------------
__global__ __launch_bounds__(256) void x1_kernel(
    const void* __restrict__ x, const unsigned short* __restrict__ P1,
    const void* __restrict__ b1, unsigned short* __restrict__ X1,
    const int* __restrict__ flags, int N) {
  __shared__ unsigned short hs[64][264];
  const bool f32 = flags[0] != 0;
  const int tid = threadIdx.x, lane = tid & 63, wid = tid >> 6;
  const int l15 = lane & 15, quad = lane >> 4;
  const int base = blockIdx.x * 64;
  int mn = min(base + wid * 16 + l15, N - 1);

  f32x4 zero = {0.f, 0.f, 0.f, 0.f};
  f32x4 acca[8], accb[8];
#pragma unroll
  for (int ct = 0; ct < 8; ct++) { acca[ct] = zero; accb[ct] = zero; }
#pragma unroll
  for (int ks = 0; ks < 4; ks++) {
    short8 a = load_a8(x, (size_t)mn, ks * 32 + quad * 8, f32);
    const unsigned short* wpa = P1 + ((size_t)(ks * 8) * 64 + lane) * 8;
    const unsigned short* wpb = P1 + ((size_t)((ks + 4) * 8) * 64 + lane) * 8;
#pragma unroll
    for (int ct = 0; ct < 8; ct++) {
      short8 ba = *(const short8*)(wpa + ct * 512);
      short8 bb = *(const short8*)(wpb + ct * 512);
      acca[ct] = __builtin_amdgcn_mfma_f32_16x16x32_bf16(a, ba, acca[ct], 0, 0, 0);
      accb[ct] = __builtin_amdgcn_mfma_f32_16x16x32_bf16(a, bb, accb[ct], 0, 0, 0);
    }
  }
#pragma unroll
  for (int ct = 0; ct < 8; ct++) {
    const int col = ct * 16 + l15;
    const float bv = loads(b1, col, f32);
#pragma unroll
    for (int r = 0; r < 4; r++) {
      hs[wid * 16 + quad * 4 + r][col]       = f2bf(acca[ct][r] + bv);
      hs[wid * 16 + quad * 4 + r][128 + col] = f2bf(accb[ct][r]);
    }
  }
  __syncthreads();
  const int row = tid >> 2, part = tid & 3;
  if (base + row < N) {
    unsigned short* op = X1 + (size_t)(base + row) * 256 + part * 64;
#pragma unroll
    for (int j = 0; j < 8; j++)
      *(short8*)(op + j * 8) = *(const short8*)&hs[row][part * 64 + j * 8];
  }
}

// ---------------------------------------------------------------------------
// edgeS v3: per 64 SORTED edges (by dst): eattr[perm[e]]@W1c -> +X1a[src]
// +X1b[dst] relu -> @W2 + b2 -> in-LDS segmented reduce by dst in TWO 64-col
// passes (halves LDS: ms[64][68] f32 == hs[64][136] bf16 == 17408 B) so the
// block footprint is ~18 KB -> 8 blocks/CU -> 32 waves (was 16).  Messages
// never touch HBM; boundary atomics only.
// ---------------------------------------------------------------------------
__global__ __launch_bounds__(256, 8) void edgeS_kernel(
    const void* __restrict__ eattr, const int* __restrict__ ssrc,
    const int* __restrict__ sdst, const int* __restrict__ perm,
    const unsigned short* __restrict__ X1,
    const unsigned short* __restrict__ P1, const unsigned short* __restrict__ P2,
    const void* __restrict__ b2, float* __restrict__ aggf,
    const int* __restrict__ flags, int E, int N) {
  __shared__ __align__(16) char smem[64 * 136 * 2];   // hs bf16 unioned with ms[64][68] f32
  __shared__ int sdst_s[64], ssrc_s[64];
  unsigned short (*hs)[136] = (unsigned short (*)[136])smem;
  float (*ms)[68] = (float (*)[68])smem;
  const bool f32 = flags[0] != 0;
  const int tid = threadIdx.x, lane = tid & 63, wid = tid >> 6;
  const int l15 = lane & 15, quad = lane >> 4;
  const int base = blockIdx.x * 64;

  if (tid < 64) {
    int e = min(base + tid, E - 1);
    sdst_s[tid] = sdst[e];
    ssrc_s[tid] = ssrc[e];
  }

  const int me = min(base + wid * 16 + l15, E - 1);
  const int pe = perm[me];

  // GEMM1: eattr[pe] @ W1c  (W1 rows 256..383 = P1 ks 8..11)
  f32x4 zero = {0.f, 0.f, 0.f, 0.f};
  f32x4 acc[8];
#pragma unroll
  for (int ct = 0; ct < 8; ct++) acc[ct] = zero;
#pragma unroll
  for (int ks = 0; ks < 4; ks++) {
    short8 a = load_a8(eattr, (size_t)pe, ks * 32 + quad * 8, f32);
    const unsigned short* wp = P1 + ((size_t)((ks + 8) * 8) * 64 + lane) * 8;
#pragma unroll
    for (int ct = 0; ct < 8; ct++) {
      short8 b = *(const short8*)(wp + ct * 512);
      acc[ct] = __builtin_amdgcn_mfma_f32_16x16x32_bf16(a, b, acc[ct], 0, 0, 0);
    }
  }
#pragma unroll
  for (int ct = 0; ct < 8; ct++) {
    const int col = ct * 16 + l15;
#pragma unroll
    for (int r = 0; r < 4; r++)
      hs[wid * 16 + quad * 4 + r][col] = f2bf(acc[ct][r]);
  }
  __syncthreads();  // publishes ssrc_s/sdst_s (hs rows stay wave-private)

  // Add X1a[src] + X1b[dst], ReLU — wave-private rows (wid*16 + lane/4),
  // 4 lanes per row reading contiguous 16 B chunks.
  {
    const int r = wid * 16 + (lane >> 2);
    const int cq = (lane & 3) * 8;          // 16 B sub-chunk
    const int s = ssrc_s[r], d = sdst_s[r];
    const unsigned short* ap = X1 + (size_t)s * 256;
    const unsigned short* bp = X1 + (size_t)d * 256 + 128;
#pragma unroll
    for (int j = 0; j < 4; j++) {
      const int c0 = cq + j * 32;
      short8 h8 = *(const short8*)&hs[r][c0];
      short8 a8 = *(const short8*)(ap + c0);
      short8 b8 = *(const short8*)(bp + c0);
      short8 o;
#pragma unroll
      for (int k = 0; k < 8; k++) {
        float v = bf2f((unsigned short)h8[k]) + bf2f((unsigned short)a8[k])
                + bf2f((unsigned short)b8[k]);
        o[k] = (short)f2bf(fmaxf(v, 0.f));
      }
      *(short8*)&hs[r][c0] = o;
    }
  }

  // GEMM2: h @ W2 (wave-private rows, no barrier needed since add was same-wave).
  f32x4 acc2[8];
#pragma unroll
  for (int ct = 0; ct < 8; ct++) acc2[ct] = zero;
#pragma unroll
  for (int ks = 0; ks < 4; ks++) {
    short8 a = *(const short8*)&hs[wid * 16 + l15][ks * 32 + quad * 8];
    const unsigned short* wp = P2 + ((size_t)(ks * 8) * 64 + lane) * 8;
#pragma unroll
    for (int ct = 0; ct < 8; ct++) {
      short8 b = *(const short8*)(wp + ct * 512);
      acc2[ct] = __builtin_amdgcn_mfma_f32_16x16x32_bf16(a, b, acc2[ct], 0, 0, 0);
    }
  }
  float b2v[8];
#pragma unroll
  for (int ct = 0; ct < 8; ct++) b2v[ct] = loads(b2, ct * 16 + l15, f32);

  // Two 64-column passes: write fp32 messages into ms[64][68], segmented
  // reduce over sorted dst (4 threads/col, 16 rows each), boundary atomics.
#pragma unroll
  for (int h = 0; h < 2; h++) {
    __syncthreads();  // h=0: all hs reads done; h=1: previous reduce done
#pragma unroll
    for (int c = 0; c < 4; c++) {
      const int ct = h * 4 + c;
      const int colh = c * 16 + l15;
#pragma unroll
      for (int r = 0; r < 4; r++) {
        const int e = base + wid * 16 + quad * 4 + r;
        ms[wid * 16 + quad * 4 + r][colh] = (e < E) ? (acc2[ct][r] + b2v[ct]) : 0.0f;
      }
    }
    __syncthreads();
    const int colh = tid & 63;
    const int col  = h * 64 + colh;
    const int grp  = tid >> 6;
    const int r0   = grp * 16;
    float sum = 0.0f;
    int cur = sdst_s[r0];
#pragma unroll 4
    for (int r = r0; r < r0 + 16; r++) {
      int d = sdst_s[r];
      if (d != cur) {
        atomicAdd(&aggf[(size_t)cur * HID + col], sum);
        sum = 0.0f; cur = d;
      }
      sum += ms[r][colh];
    }
    atomicAdd(&aggf[(size_t)cur * HID + col], sum);
  }
}

// ---------------------------------------------------------------------------
// Mode-2 fallback kernels (round-3 structure, kept intact).
// ---------------------------------------------------------------------------
__global__ __launch_bounds__(1024) void scan_kernel(const int* __restrict__ counts,
                                                    int* __restrict__ offs, int N) {
  __shared__ int wsum[16];
  __shared__ int wpre[16];
  __shared__ int carry_s;
  const int tid = threadIdx.x, lane = tid & 63, wid = tid >> 6;
  if (tid == 0) carry_s = 0;
  __syncthreads();
  for (int base = 0; base < N; base += 1024) {
    int i = base + tid;
    int v = (i < N) ? counts[i] : 0;
    int s = v;
#pragma unroll
    for (int off = 1; off < 64; off <<= 1) {
      int t = __shfl_up(s, off, 64);
      if (lane >= off) s += t;
    }
    if (lane == 63) wsum[wid] = s;
    __syncthreads();
    if (tid == 0) {
      int run = carry_s;
#pragma unroll
      for (int w = 0; w < 16; w++) { int t = wsum[w]; wpre[w] = run; run += t; }
      carry_s = run;
    }
    __syncthreads();
    if (i < N) offs[i] = wpre[wid] + s - v;
    __syncthreads();
  }
  if (tid == 0) offs[N] = carry_s;
}

__global__ void scatter_kernel(const int* __restrict__ eidx, int* __restrict__ cur,
                               int* __restrict__ ssrc, int* __restrict__ sdst,
                               int* __restrict__ perm,
                               const int* __restrict__ flags, int E, int N) {
  const bool i64 = flags[1] != 0;
  int e = blockIdx.x * 256 + threadIdx.x;
  if (e < E) {
    int d = get_dst(eidx, i64, E, e);
    int s = get_src(eidx, i64, E, e);
    d = min(max(d, 0), N - 1);
    s = min(max(s, 0), N - 1);
    int pos = atomicAdd(&cur[d], 1);
    ssrc[pos] = s;
    sdst[pos] = d;
    perm[pos] = e;
  }
}

__global__ __launch_bounds__(256) void edge_kernel_sorted(
    const void* __restrict__ x, const void* __restrict__ eattr,
    const int* __restrict__ ssrc, const int* __restrict__ sdst,
    const int* __restrict__ perm,
    const unsigned short* __restrict__ P1, const void* __restrict__ b1,
    const unsigned short* __restrict__ P2, const void* __restrict__ b2,
    float* __restrict__ aggf, const int* __restrict__ flags, int E, int N) {
  __shared__ __align__(16) char smem[64 * 132 * 4];
  __shared__ int sdst_s[64];
  unsigned short (*hs)[136] = (unsigned short (*)[136])smem;
  float (*ms)[132] = (float (*)[132])smem;
  const bool f32 = flags[0] != 0;
  const int tid = threadIdx.x, lane = tid & 63, wid = tid >> 6;
  const int l15 = lane & 15, quad = lane >> 4;
  const int base = blockIdx.x * 64;

  if (tid < 64) sdst_s[tid] = sdst[min(base + tid, E - 1)];

  int me = base + wid * 16 + l15;
  if (me >= E) me = E - 1;
  const int src = ssrc[me];
  const int dsm = sdst[me];
  const int pe  = perm[me];

  f32x4 zero = {0.f, 0.f, 0.f, 0.f};
  f32x4 acc[8];
#pragma unroll
  for (int ct = 0; ct < 8; ct++) acc[ct] = zero;
#pragma unroll
  for (int ks = 0; ks < 12; ks++) {
    const int k0 = ks * 32;
    short8 a;
    if (k0 < 128)      a = load_a8(x,     (size_t)src, k0 + quad * 8, f32);
    else if (k0 < 256) a = load_a8(x,     (size_t)dsm, (k0 - 128) + quad * 8, f32);
    else               a = load_a8(eattr, (size_t)pe,  (k0 - 256) + quad * 8, f32);
    const unsigned short* wp = P1 + ((size_t)(ks * 8) * 64 + lane) * 8;
#pragma unroll
    for (int ct = 0; ct < 8; ct++) {
      short8 b = *(const short8*)(wp + ct * 512);
      acc[ct] = __builtin_amdgcn_mfma_f32_16x16x32_bf16(a, b, acc[ct], 0, 0, 0);
    }
  }
#pragma unroll
  for (int ct = 0; ct < 8; ct++) {
    const int col = ct * 16 + l15;
    const float bv = loads(b1, col, f32);
#pragma unroll
    for (int r = 0; r < 4; r++)
      hs[wid * 16 + quad * 4 + r][col] = f2bf(fmaxf(acc[ct][r] + bv, 0.f));
  }
  f32x4 acc2[8];
#pragma unroll
  for (int ct = 0; ct < 8; ct++) acc2[ct] = zero;
#pragma unroll
  for (int ks = 0; ks < 4; ks++) {
    short8 a = *(const short8*)&hs[wid * 16 + l15][ks * 32 + quad * 8];
    const unsigned short* wp = P2 + ((size_t)(ks * 8) * 64 + lane) * 8;
#pragma unroll
    for (int ct = 0; ct < 8; ct++) {
      short8 b = *(const short8*)(wp + ct * 512);
      acc2[ct] = __builtin_amdgcn_mfma_f32_16x16x32_bf16(a, b, acc2[ct], 0, 0, 0);
    }
  }
  float b2v[8];
#pragma unroll
  for (int ct = 0; ct < 8; ct++) b2v[ct] = loads(b2, ct * 16 + l15, f32);
  __syncthreads();
#pragma unroll
  for (int ct = 0; ct < 8; ct++) {
    const int col = ct * 16 + l15;
#pragma unroll
    for (int r = 0; r < 4; r++) {
      const int e = base + wid * 16 + quad * 4 + r;
      ms[wid * 16 + quad * 4 + r][col] = (e < E) ? (acc2[ct][r] + b2v[ct]) : 0.0f;
    }
  }
  __syncthreads();
  const int col  = tid & 127;
  const int half = tid >> 7;
  const int r0 = half * 32;
  float sum = 0.0f;
  int cur = sdst_s[r0];
#pragma unroll 4
  for (int r = r0; r < r0 + 32; r++) {
    int d = sdst_s[r];
    if (d != cur) {
      atomicAdd(&aggf[(size_t)cur * HID + col], sum);
      sum = 0.0f; cur = d;
    }
    sum += ms[r][col];
  }
  atomicAdd(&aggf[(size_t)cur * HID + col], sum);
}

__global__ __launch_bounds__(256) void edge_kernel_plain(
    const void* __restrict__ x, const int* __restrict__ eidx,
    const void* __restrict__ eattr,
    const unsigned short* __restrict__ P1, const void* __restrict__ b1,
    const unsigned short* __restrict__ P2, const void* __restrict__ b2,
    float* __restrict__ aggf, void* __restrict__ out,
    const int* __restrict__ flags, int E, int N, int small_mode) {
  __shared__ unsigned short hs[64][136];
  const bool f32 = flags[0] != 0;
  const bool i64 = flags[1] != 0;
  const int tid = threadIdx.x, lane = tid & 63, wid = tid >> 6;
  const int l15 = lane & 15, quad = lane >> 4;
  const int base = blockIdx.x * 64;

  int me = base + wid * 16 + l15;
  if (me >= E) me = E - 1;
  int src = get_src(eidx, i64, E, me);
  int dsm = get_dst(eidx, i64, E, me);
  src = min(max(src, 0), N - 1);
  dsm = min(max(dsm, 0), N - 1);

  f32x4 zero = {0.f, 0.f, 0.f, 0.f};
  f32x4 acc[8];
#pragma unroll
  for (int ct = 0; ct < 8; ct++) acc[ct] = zero;
#pragma unroll
  for (int ks = 0; ks < 12; ks++) {
    const int k0 = ks * 32;
    short8 a;
    if (k0 < 128)      a = load_a8(x,     (size_t)src, k0 + quad * 8, f32);
    else if (k0 < 256) a = load_a8(x,     (size_t)dsm, (k0 - 128) + quad * 8, f32);
    else               a = load_a8(eattr, (size_t)me,  (k0 - 256) + quad * 8, f32);
    const unsigned short* wp = P1 + ((size_t)(ks * 8) * 64 + lane) * 8;
#pragma unroll
    for (int ct = 0; ct < 8; ct++) {
      short8 b = *(const short8*)(wp + ct * 512);
      acc[ct] = __builtin_amdgcn_mfma_f32_16x16x32_bf16(a, b, acc[ct], 0, 0, 0);
    }
  }
#pragma unroll
  for (int ct = 0; ct < 8; ct++) {
    const int col = ct * 16 + l15;
    const float bv = loads(b1, col, f32);
#pragma unroll
    for (int r = 0; r < 4; r++)
      hs[wid * 16 + quad * 4 + r][col] = f2bf(fmaxf(acc[ct][r] + bv, 0.f));
  }
  __syncthreads();
  f32x4 acc2[8];
#pragma unroll
  for (int ct = 0; ct < 8; ct++) acc2[ct] = zero;
#pragma unroll
  for (int ks = 0; ks < 4; ks++) {
    short8 a = *(const short8*)&hs[wid * 16 + l15][ks * 32 + quad * 8];
    const unsigned short* wp = P2 + ((size_t)(ks * 8) * 64 + lane) * 8;
#pragma unroll
    for (int ct = 0; ct < 8; ct++) {
      short8 b = *(const short8*)(wp + ct * 512);
      acc2[ct] = __builtin_amdgcn_mfma_f32_16x16x32_bf16(a, b, acc2[ct], 0, 0, 0);
    }
  }
  float b2v[8];
#pragma unroll
  for (int ct = 0; ct < 8; ct++) b2v[ct] = loads(b2, ct * 16 + l15, f32);

  if (!small_mode || f32) {
    float* tgt = (!small_mode) ? aggf : (float*)out;
#pragma unroll
    for (int r = 0; r < 4; r++) {
      const int e = base + wid * 16 + quad * 4 + r;
      if (e < E) {
        int d = get_dst(eidx, i64, E, e);
        d = min(max(d, 0), N - 1);
        float* op = tgt + (size_t)d * HID + l15;
#pragma unroll
        for (int ct = 0; ct < 8; ct++) atomicAdd(op + ct * 16, acc2[ct][r] + b2v[ct]);
      }
    }
  } else {
#pragma unroll
    for (int ct = 0; ct < 8; ct++) {
      const int col = ct * 16 + l15;
#pragma unroll
      for (int r = 0; r < 4; r++)
        hs[wid * 16 + quad * 4 + r][col] = f2bf(acc2[ct][r] + b2v[ct]);
    }
    __syncthreads();
    const int row = tid >> 2;
    const int cg  = (tid & 3) * 32;
    const int e = base + row;
    if (e < E) {
      int d = get_dst(eidx, i64, E, e);
      d = min(max(d, 0), N - 1);
      unsigned int* orow = (unsigned int*)out + ((size_t)d * HID >> 1);
#pragma unroll
      for (int p = 0; p < 16; p++) {
        const int col = cg + p * 2;
        const float lo = bf2f(hs[row][col]);
        const float hi = bf2f(hs[row][col + 1]);
        unsigned int* wp = orow + (col >> 1);
        unsigned int old = *wp, assumed;
        do {
          assumed = old;
          unsigned int nv = (unsigned int)f2bf(bf2f((unsigned short)(assumed & 0xFFFF)) + lo)
                          | ((unsigned int)f2bf(bf2f((unsigned short)(assumed >> 16)) + hi) << 16);
          old = atomicCAS(wp, assumed, nv);
        } while (old != assumed);
      }
    }
  }
}

// ---------------------------------------------------------------------------
// Node kernel: u = relu([x|agg]@U1+ub1); upd = u@U2+ub2; out = LN(x+upd)*g+b
// ---------------------------------------------------------------------------
__global__ __launch_bounds__(256) void node_kernel(
    const void* __restrict__ x, const float* __restrict__ aggf,
    const unsigned short* __restrict__ PU1, const void* __restrict__ ub1,
    const unsigned short* __restrict__ PU2, const void* __restrict__ ub2,
    const void* __restrict__ gamma, const void* __restrict__ beta,
    void* __restrict__ out, const int* __restrict__ flags, int N, int small_mode) {
  __shared__ unsigned short hs[64][136];
  const bool f32 = flags[0] != 0;
  const int tid = threadIdx.x, lane = tid & 63, wid = tid >> 6;
  const int l15 = lane & 15, quad = lane >> 4;
  const int base = blockIdx.x * 64;

  int mn = base + wid * 16 + l15;
  if (mn >= N) mn = N - 1;

  const void* aggp = (!small_mode) ? (const void*)aggf : (const void*)out;
  const bool aggF32 = (!small_mode) ? true : f32;

  f32x4 zero = {0.f, 0.f, 0.f, 0.f};
  f32x4 acc[8];
#pragma unroll
  for (int ct = 0; ct < 8; ct++) acc[ct] = zero;
#pragma unroll
  for (int ks = 0; ks < 8; ks++) {
    const int k0 = ks * 32;
    short8 a;
    if (k0 < 128) a = load_a8(x,    (size_t)mn, k0 + quad * 8, f32);
    else          a = load_a8(aggp, (size_t)mn, (k0 - 128) + quad * 8, aggF32);
    const unsigned short* wp = PU1 + ((size_t)(ks * 8) * 64 + lane) * 8;
#pragma unroll
    for (int ct = 0; ct < 8; ct++) {
      short8 b = *(const short8*)(wp + ct * 512);
      acc[ct] = __builtin_amdgcn_mfma_f32_16x16x32_bf16(a, b, acc[ct], 0, 0, 0);
    }
  }
#pragma unroll
  for (int ct = 0; ct < 8; ct++) {
    const int col = ct * 16 + l15;
    const float bv = loads(ub1, col, f32);
#pragma unroll
    for (int r = 0; r < 4; r++)
      hs[wid * 16 + quad * 4 + r][col] = f2bf(fmaxf(acc[ct][r] + bv, 0.f));
  }
  __syncthreads();
  f32x4 acc2[8];
#pragma unroll
  for (int ct = 0; ct < 8; ct++) acc2[ct] = zero;
#pragma unroll
  for (int ks = 0; ks < 4; ks++) {
    short8 a = *(const short8*)&hs[wid * 16 + l15][ks * 32 + quad * 8];
    const unsigned short* wp = PU2 + ((size_t)(ks * 8) * 64 + lane) * 8;
#pragma unroll
    for (int ct = 0; ct < 8; ct++) {
      short8 b = *(const short8*)(wp + ct * 512);
      acc2[ct] = __builtin_amdgcn_mfma_f32_16x16x32_bf16(a, b, acc2[ct], 0, 0, 0);
    }
  }

  float vals[8][4];
  float s1[4] = {0.f, 0.f, 0.f, 0.f};
  float s2[4] = {0.f, 0.f, 0.f, 0.f};
#pragma unroll
  for (int ct = 0; ct < 8; ct++) {
    const int col = ct * 16 + l15;
    const float bv = loads(ub2, col, f32);
#pragma unroll
    for (int r = 0; r < 4; r++) {
      int row = base + wid * 16 + quad * 4 + r;
      int rc = row < N ? row : 0;
      float v = acc2[ct][r] + bv + loads(x, (size_t)rc * HID + col, f32);
      vals[ct][r] = v;
      s1[r] += v;
      s2[r] += v * v;
    }
  }
#pragma unroll
  for (int off = 1; off < 16; off <<= 1) {
#pragma unroll
    for (int r = 0; r < 4; r++) {
      s1[r] += __shfl_xor(s1[r], off, 16);
      s2[r] += __shfl_xor(s2[r], off, 16);
    }
  }
#pragma unroll
  for (int r = 0; r < 4; r++) {
    const int row = base + wid * 16 + quad * 4 + r;
    if (row < N) {
      const float mean = s1[r] * (1.0f / 128.0f);
      const float var  = fmaxf(s2[r] * (1.0f / 128.0f) - mean * mean, 0.0f);
      const float rstd = rsqrtf(var + 1e-5f);
#pragma unroll
      for (int ct = 0; ct < 8; ct++) {
        const int col = ct * 16 + l15;
        float o = (vals[ct][r] - mean) * rstd * loads(gamma, col, f32) + loads(beta, col, f32);
        if (f32) ((float*)out)[(size_t)row * HID + col] = o;
        else     ((unsigned short*)out)[(size_t)row * HID + col] = f2bf(o);
      }
    }
  }
}

// ---------------------------------------------------------------------------
extern "C" void kernel_launch(void* const* d_in, const int* in_sizes, int n_in,
                              void* d_out, int out_size, void* d_ws, size_t ws_size,
                              hipStream_t stream) {
  (void)n_in;
  const void* x     = d_in[0];
  const int*  eidx  = (const int*)d_in[1];
  const void* eattr = d_in[2];
  const void* W1  = d_in[3];
  const void* b1  = d_in[4];
  const void* W2  = d_in[5];
  const void* b2  = d_in[6];
  const void* U1  = d_in[7];
  const void* ub1 = d_in[8];
  const void* U2  = d_in[9];
  const void* ub2 = d_in[10];
  const void* gam = d_in[11];
  const void* bet = d_in[12];

  const int N = in_sizes[0] / HID;
  const int E = in_sizes[2] / HID;

  char* ws = (char*)d_ws;
  auto alignup = [](size_t v) { return (v + 255) & ~(size_t)255; };

  int* flags = (int*)ws;                                       // 256 B
  unsigned short* P1  = (unsigned short*)(ws + 256);
  unsigned short* P2  = (unsigned short*)(ws + 256 + 98304);
  unsigned short* PU1 = (unsigned short*)(ws + 256 + 131072);
  unsigned short* PU2 = (unsigned short*)(ws + 256 + 196608);
  const size_t agg_off = 256 + 229376;
  float* aggf = (float*)(ws + agg_off);
  const size_t agg_bytes = (size_t)N * HID * sizeof(float);
  const size_t need_basic = agg_off + agg_bytes;

  // ---- mode-3 layout: sort + X1 precompute + fused sorted edge kernel ----
  size_t o3 = alignup(need_basic);
  size_t cnt_off  = o3; o3 = alignup(o3 + (size_t)(N + 64) * 4);
  size_t cur_off  = o3; o3 = alignup(o3 + (size_t)(N + 64) * 4);
  size_t bsum_off = o3; o3 = alignup(o3 + 1024);
  size_t src3_off = o3; o3 = alignup(o3 + (size_t)E * 4);
  size_t dst3_off = o3; o3 = alignup(o3 + (size_t)E * 4);
  size_t prm3_off = o3; o3 = alignup(o3 + (size_t)E * 4);
  size_t x1_off   = o3; o3 = alignup(o3 + (size_t)N * 256 * 2);
  const size_t need3 = o3;

  // ---- mode-2 layout (round-3) ----
  size_t o2 = alignup(need_basic);
  size_t offs_off = o2; o2 = alignup(o2 + (size_t)(N + 1) * 4);
  size_t cur2_off = o2; o2 = alignup(o2 + (size_t)(N + 1) * 4);
  size_t ssrc_off = o2; o2 = alignup(o2 + (size_t)E * 4);
  size_t sds2_off = o2; o2 = alignup(o2 + (size_t)E * 4);
  size_t perm_off = o2; o2 = alignup(o2 + (size_t)E * 4);
  const size_t need2 = o2;

  const int mode = (ws_size >= need3) ? 3
                 : (ws_size >= need2) ? 2
                 : (ws_size >= need_basic) ? 1 : 0;

  detect_kernel<<<1, 256, 0, stream>>>(x, eidx, flags);
  repack_all<<<448, 256, 0, stream>>>(W1, W2, U1, U2, P1, P2, PU1, PU2, flags);

  if (mode == 3) {
    int* cntb = (int*)(ws + cnt_off);
    int* curb = (int*)(ws + cur_off);
    int* bsum = (int*)(ws + bsum_off);
    int* ssrc = (int*)(ws + src3_off);
    int* sdst = (int*)(ws + dst3_off);
    int* perm = (int*)(ws + prm3_off);
    unsigned short* X1 = (unsigned short*)(ws + x1_off);
    const int nb = (N + 1023) / 1024;

    hipMemsetAsync(aggf, 0, agg_bytes, stream);
    hipMemsetAsync(cntb, 0, (size_t)N * 4, stream);
    hist_kernel<<<(E + 255) / 256, 256, 0, stream>>>(eidx, cntb, flags, E, N);
    scanA_kernel<<<nb, 1024, 0, stream>>>(cntb, curb, bsum, N);
    scanB_kernel<<<1, 64, 0, stream>>>(bsum, nb);
    scanC_kernel<<<nb, 1024, 0, stream>>>(curb, bsum, N);
    scatter_kernel<<<(E + 255) / 256, 256, 0, stream>>>(eidx, curb, ssrc, sdst, perm,
                                                        flags, E, N);
    x1_kernel<<<(N + 63) / 64, 256, 0, stream>>>(x, P1, b1, X1, flags, N);
    edgeS_kernel<<<(E + 63) / 64, 256, 0, stream>>>(eattr, ssrc, sdst, perm, X1,
                                                    P1, P2, b2, aggf, flags, E, N);
    node_kernel<<<(N + 63) / 64, 256, 0, stream>>>(x, aggf, PU1, ub1, PU2, ub2,
                                                   gam, bet, d_out, flags, N, 0);
  } else if (mode == 2) {
    int* offsb = (int*)(ws + offs_off);
    int* curb  = (int*)(ws + cur2_off);
    int* ssrc  = (int*)(ws + ssrc_off);
    int* sdst  = (int*)(ws + sds2_off);
    int* perm  = (int*)(ws + perm_off);
    hipMemsetAsync(aggf, 0, agg_bytes, stream);
    hipMemsetAsync(curb, 0, (size_t)(N + 1) * 4, stream);
    hist_kernel<<<(E + 255) / 256, 256, 0, stream>>>(eidx, curb, flags, E, N);
    scan_kernel<<<1, 1024, 0, stream>>>(curb, offsb, N);
    hipMemcpyAsync(curb, offsb, (size_t)(N + 1) * 4, hipMemcpyDeviceToDevice, stream);
    scatter_kernel<<<(E + 255) / 256, 256, 0, stream>>>(eidx, curb, ssrc, sdst, perm,
                                                        flags, E, N);
    edge_kernel_sorted<<<(E + 63) / 64, 256, 0, stream>>>(x, eattr, ssrc, sdst, perm,
                                                          P1, b1, P2, b2, aggf, flags, E, N);
    node_kernel<<<(N + 63) / 64, 256, 0, stream>>>(x, aggf, PU1, ub1, PU2, ub2,
                                                   gam, bet, d_out, flags, N, 0);
  } else if (mode == 1) {
    hipMemsetAsync(aggf, 0, agg_bytes, stream);
    edge_kernel_plain<<<(E + 63) / 64, 256, 0, stream>>>(x, eidx, eattr, P1, b1, P2, b2,
                                                         aggf, d_out, flags, E, N, 0);
    node_kernel<<<(N + 63) / 64, 256, 0, stream>>>(x, aggf, PU1, ub1, PU2, ub2,
                                                   gam, bet, d_out, flags, N, 0);
  } else {
    zero_out_kernel<<<1024, 256, 0, stream>>>((unsigned int*)d_out, flags, (long long)out_size);
    edge_kernel_plain<<<(E + 63) / 64, 256, 0, stream>>>(x, eidx, eattr, P1, b1, P2, b2,
                                                         aggf, d_out, flags, E, N, 1);
    node_kernel<<<(N + 63) / 64, 256, 0, stream>>>(x, aggf, PU1, ub1, PU2, ub2,
                                                   gam, bet, d_out, flags, N, 1);
  }
}